// Round 8
// baseline (182.529 us; speedup 1.0000x reference)
//
#include <hip/hip_runtime.h>
#include <stdint.h>
#include <stddef.h>

// MHA: x[2,2048,1024] -> QKV proj (bf16 MFMA) -> flash attn (H=16, Dh=64) -> out proj.
// R8: V^T produced by a swapped-operand GEMM (A=wv^T, B=x -> C[d][token], coalesced;
//     kills R5-R7's 4KB-stride scatter). attn: V^T frags register-double-buffered one
//     full tile ahead; ONE counted vmcnt(8) per tile (V drains under the K wait).

typedef __attribute__((ext_vector_type(8))) short short8;
typedef __attribute__((ext_vector_type(4))) float f32x4;
typedef __attribute__((ext_vector_type(16))) float f32x16;
typedef __attribute__((ext_vector_type(4))) unsigned short u16x4;

#define MFMA16(a, b, c) __builtin_amdgcn_mfma_f32_16x16x32_bf16((a), (b), (c), 0, 0, 0)
#define MFMA32(a, b, c) __builtin_amdgcn_mfma_f32_32x32x16_bf16((a), (b), (c), 0, 0, 0)
#define AS1 __attribute__((address_space(1)))
#define AS3 __attribute__((address_space(3)))

__device__ __forceinline__ unsigned short f2bf(float f) {
  union { float f; unsigned u; } v; v.f = f;
  unsigned r = v.u + 0x7fffu + ((v.u >> 16) & 1u);   // RNE
  return (unsigned short)(r >> 16);
}

__device__ __forceinline__ unsigned cvt_pk_bf16(float lo, float hi) {
  unsigned r;
  asm("v_cvt_pk_bf16_f32 %0, %1, %2" : "=v"(r) : "v"(lo), "v"(hi));
  return r;
}

__device__ __forceinline__ void pl32_swap(unsigned& a, unsigned& b) {
  asm volatile("v_permlane32_swap_b32 %0, %1" : "+v"(a), "+v"(b));
}

__device__ __forceinline__ short8 mk8(unsigned a, unsigned b, unsigned c, unsigned d) {
  union { unsigned u[4]; short8 s; } v;
  v.u[0] = a; v.u[1] = b; v.u[2] = c; v.u[3] = d;
  return v.s;
}

// ---------------- prep ----------------
__global__ __launch_bounds__(256) void cast_x_kernel(const float* __restrict__ x,
                                                     unsigned short* __restrict__ xb) {
  int i = (blockIdx.x * 256 + threadIdx.x) * 4;
  float4 v = *reinterpret_cast<const float4*>(x + i);
  u16x4 o;
  o.x = f2bf(v.x); o.y = f2bf(v.y); o.z = f2bf(v.z); o.w = f2bf(v.w);
  *reinterpret_cast<u16x4*>(xb + i) = o;
}

__global__ __launch_bounds__(256) void prep_w_kernel(const float* __restrict__ wq,
                                                     const float* __restrict__ wk,
                                                     const float* __restrict__ wv,
                                                     const float* __restrict__ wo,
                                                     unsigned short* __restrict__ wt) {
  __shared__ unsigned short t_lds[32][33];
  int bid = blockIdx.x;
  int wsel = bid >> 10;
  int rem = bid & 1023;
  int kb = (rem >> 5) << 5;
  int nb = (rem & 31) << 5;
  const float* W = (wsel == 0) ? wq : (wsel == 1) ? wk : (wsel == 2) ? wv : wo;
  int t = threadIdx.x;
  int r = t >> 3, c = (t & 7) * 4;
  float4 v = *reinterpret_cast<const float4*>(W + (size_t)(kb + r) * 1024 + nb + c);
  t_lds[r][c + 0] = f2bf(v.x);
  t_lds[r][c + 1] = f2bf(v.y);
  t_lds[r][c + 2] = f2bf(v.z);
  t_lds[r][c + 3] = f2bf(v.w);
  __syncthreads();
  u16x4 o;
  o.x = t_lds[c + 0][r]; o.y = t_lds[c + 1][r];
  o.z = t_lds[c + 2][r]; o.w = t_lds[c + 3][r];
  *reinterpret_cast<u16x4*>(wt + (size_t)(wsel * 1024 + nb + r) * 1024 + kb + c) = o;
}

__global__ __launch_bounds__(256) void pack_bias_kernel(const float* __restrict__ bq,
                                                        const float* __restrict__ bk,
                                                        const float* __restrict__ bv,
                                                        float* __restrict__ bias3) {
  int i = blockIdx.x * 256 + threadIdx.x;
  if (i < 3072) bias3[i] = (i < 1024) ? bq[i] : (i < 2048) ? bk[i - 1024] : bv[i - 2048];
}

// ---------------- GEMM: 2-phase dbuf, single barrier per K-step ----------------
// MODE 0: out-proj  C[4096][1024] fp32, bias[n].
// MODE 1: QK        C[4096][2048] bf16, bias[n], Q cols (<1024) scaled by 0.125*log2e.
// MODE 2: V^T       C[1024][4096] bf16 (A=wv^T, Bt=x), bias[m] (row bias).
template <int MODE>
__global__ __launch_bounds__(256) void gemm_bt_kernel(const unsigned short* __restrict__ A,
                                                      const unsigned short* __restrict__ Bt,
                                                      const float* __restrict__ bias,
                                                      float* __restrict__ Cf,
                                                      unsigned short* __restrict__ Cb,
                                                      int N) {
  constexpr int K = 1024;
  constexpr int MT = (MODE == 2) ? 8 : 32;           // M/128
  __shared__ __align__(16) unsigned short a_lds[2][128 * 32];
  __shared__ __align__(16) unsigned short b_lds[2][128 * 32];
  const int nb = N >> 7;
  const int nwg = nb * MT;
  const int cpx = nwg >> 3;
  const int wg = ((int)blockIdx.x & 7) * cpx + ((int)blockIdx.x >> 3);  // XCD swizzle
  const int bm = wg / nb;
  const int bn = wg % nb;
  const int m0 = bm << 7, n0 = bn << 7;
  const int tid = threadIdx.x;
  const int w = tid >> 6, l = tid & 63;
  const int lr = l & 15, lg = l >> 4;
  const int wm = (w >> 1) << 6, wn = (w & 1) << 6;

  const int q0 = w * 2, q1 = w * 2 + 1;
  const unsigned short* pa0 = A + (size_t)(m0 + q0 * 16 + (l >> 2)) * K + (l & 3) * 8;
  const unsigned short* pa1 = A + (size_t)(m0 + q1 * 16 + (l >> 2)) * K + (l & 3) * 8;
  const unsigned short* pb0 = Bt + (size_t)(n0 + q0 * 16 + (l >> 2)) * K + (l & 3) * 8;
  const unsigned short* pb1 = Bt + (size_t)(n0 + q1 * 16 + (l >> 2)) * K + (l & 3) * 8;

#define GEMM_STAGE(buf, k0)                                                        \
  do {                                                                             \
    __builtin_amdgcn_global_load_lds((const AS1 void*)(pa0 + (k0)),                \
        (AS3 void*)(&a_lds[buf][q0 * 512]), 16, 0, 0);                             \
    __builtin_amdgcn_global_load_lds((const AS1 void*)(pa1 + (k0)),                \
        (AS3 void*)(&a_lds[buf][q1 * 512]), 16, 0, 0);                             \
    __builtin_amdgcn_global_load_lds((const AS1 void*)(pb0 + (k0)),                \
        (AS3 void*)(&b_lds[buf][q0 * 512]), 16, 0, 0);                             \
    __builtin_amdgcn_global_load_lds((const AS1 void*)(pb1 + (k0)),                \
        (AS3 void*)(&b_lds[buf][q1 * 512]), 16, 0, 0);                             \
  } while (0)

  f32x4 acc[4][4] = {};
  GEMM_STAGE(0, 0);
  __syncthreads();

  int cur = 0;
  for (int k0 = 0; k0 < K; k0 += 32) {
    if (k0 + 32 < K) GEMM_STAGE(cur ^ 1, k0 + 32);
    short8 af[4], bfr[4];
#pragma unroll
    for (int i = 0; i < 4; ++i)
      af[i] = *reinterpret_cast<const short8*>(&a_lds[cur][(wm + i * 16 + lr) * 32 + lg * 8]);
#pragma unroll
    for (int i = 0; i < 4; ++i)
      bfr[i] = *reinterpret_cast<const short8*>(&b_lds[cur][(wn + i * 16 + lr) * 32 + lg * 8]);
#pragma unroll
    for (int i = 0; i < 4; ++i)
#pragma unroll
      for (int j = 0; j < 4; ++j)
        acc[i][j] = MFMA16(af[i], bfr[j], acc[i][j]);
    __syncthreads();
    cur ^= 1;
  }
#undef GEMM_STAGE

#pragma unroll
  for (int i = 0; i < 4; ++i) {
#pragma unroll
    for (int j = 0; j < 4; ++j) {
#pragma unroll
      for (int r = 0; r < 4; ++r) {
        int m = m0 + wm + i * 16 + lg * 4 + r;
        int n = n0 + wn + j * 16 + lr;
        if constexpr (MODE == 0) {
          Cf[(size_t)m * N + n] = acc[i][j][r] + bias[n];
        } else if constexpr (MODE == 1) {
          const float scale = (n0 < 1024) ? 0.18033688011111f : 1.0f;  // 0.125*log2e
          Cb[(size_t)m * N + n] = f2bf((acc[i][j][r] + bias[n]) * scale);
        } else {
          Cb[(size_t)m * N + n] = f2bf(acc[i][j][r] + bias[m]);        // row bias (bv)
        }
      }
    }
  }
}

// ---------------- flash attention ----------------
// grid 2048 = (b,h)[32] x qblocks[64 of 32 rows]; 2 waves; wave w owns KV half
// [w*1024, w*1024+1024) in 32 tiles of 32 t. Fixed-base softmax -> additive partials,
// LDS merge epilogue. K: global_load_lds (pre-swizzled src) into per-wave private dbuf.
// V^T: direct-global frags, register-double-buffered ONE TILE ahead (vfa/vfb).
// One counted vmcnt(8) per tile: after issuing V(i+1)+K(i+1), exactly 8 newer ops
// remain; waiting to 8 drains K(i) AND the older V(i).
__global__ __launch_bounds__(128, 4) void attn_kernel(const unsigned short* __restrict__ qk,
                                                      const unsigned short* __restrict__ vt,
                                                      unsigned short* __restrict__ aout) {
  __shared__ __align__(16) char lds[16384];   // [wave0 K dbuf 8K][wave1 K dbuf 8K]
  const int tid = threadIdx.x;
  const int w = tid >> 6, l = tid & 63;
  const int lq = l & 31, hi = l >> 5;
  const int wg = ((int)blockIdx.x & 7) * 256 + ((int)blockIdx.x >> 3);  // XCD swizzle
  const int bh = wg >> 6, qb = wg & 63;
  const int b = bh >> 4, h = bh & 15;

  // Q fragments (B-operand), pre-scaled by 0.125*log2e in the GEMM epilogue.
  short8 qf[4];
  {
    const unsigned short* qrow = qk + (size_t)(b * 2048 + qb * 32 + lq) * 2048 + h * 64 + hi * 8;
#pragma unroll
    for (int c = 0; c < 4; ++c)
      qf[c] = *reinterpret_cast<const short8*>(qrow + c * 16);
  }

  // K staging sources (pre-swizzled; LDS linear dest). Plane = [32 t][128 B], swizzle
  // (t&7)<<4; gll chunk j covers rows j*8..j*8+7; lane row bits = l>>3.
  const int tloc = l >> 3;
  const int colsw = (16 * (l & 7)) ^ (tloc << 4);
  const char* kq = (const char*)qk +
                   (((size_t)(b * 2048 + w * 1024) * 2048 + 1024 + h * 64) << 1);
  const char* ks0 = kq + (size_t)tloc * 4096 + colsw;
  const char* ks1 = ks0 + 32768;
  const char* ks2 = ks0 + 65536;
  const char* ks3 = ks0 + 98304;

  // V^T fragment bases: vt[1024 d][4096 tok]; lane row d = h*64+lq (+32 for d-block 1).
  const unsigned short* vp0 = vt + (size_t)(h * 64 + lq) * 4096 + b * 2048 + w * 1024 + hi * 8;
  const unsigned short* vp1 = vp0 + (size_t)32 * 4096;

  const int kreg = w * 8192;
  int aoff[4];
#pragma unroll
  for (int c = 0; c < 4; ++c)
    aoff[c] = kreg + lq * 128 + ((c * 32 + hi * 16) ^ ((lq & 7) << 4));

  float ls0 = 0.f, ls1 = 0.f, ls2 = 0.f, ls3 = 0.f;
  f32x16 ot0 = {}, ot1 = {};

  // prologue: V(0) -> vfa regs; K(0) -> LDS buf 0
  short8 vfa0 = *reinterpret_cast<const short8*>(vp0);
  short8 vfa1 = *reinterpret_cast<const short8*>(vp0 + 16);
  short8 vfa2 = *reinterpret_cast<const short8*>(vp1);
  short8 vfa3 = *reinterpret_cast<const short8*>(vp1 + 16);
  vp0 += 32; vp1 += 32;
  __builtin_amdgcn_global_load_lds((const AS1 void*)ks0, (AS3 void*)(lds + kreg), 16, 0, 0);
  __builtin_amdgcn_global_load_lds((const AS1 void*)ks1, (AS3 void*)(lds + kreg + 1024), 16, 0, 0);
  __builtin_amdgcn_global_load_lds((const AS1 void*)ks2, (AS3 void*)(lds + kreg + 2048), 16, 0, 0);
  __builtin_amdgcn_global_load_lds((const AS1 void*)ks3, (AS3 void*)(lds + kreg + 3072), 16, 0, 0);
  ks0 += 131072; ks1 += 131072; ks2 += 131072; ks3 += 131072;

  short8 vfb0, vfb1, vfb2, vfb3;
  int cur = 0;

#define ATTN_TILE(VC0, VC1, VC2, VC3, VN0, VN1, VN2, VN3, MORE, WAITK)                 \
  {                                                                                    \
    if (MORE) {                                                                        \
      VN0 = *reinterpret_cast<const short8*>(vp0);                                     \
      VN1 = *reinterpret_cast<const short8*>(vp0 + 16);                                \
      VN2 = *reinterpret_cast<const short8*>(vp1);                                     \
      VN3 = *reinterpret_cast<const short8*>(vp1 + 16);                                \
      vp0 += 32; vp1 += 32;                                                            \
      const int nb_ = kreg + ((cur ^ 1) << 12);                                        \
      __builtin_amdgcn_global_load_lds((const AS1 void*)ks0, (AS3 void*)(lds + nb_), 16, 0, 0); \
      __builtin_amdgcn_global_load_lds((const AS1 void*)ks1, (AS3 void*)(lds + nb_ + 1024), 16, 0, 0); \
      __builtin_amdgcn_global_load_lds((const AS1 void*)ks2, (AS3 void*)(lds + nb_ + 2048), 16, 0, 0); \
      __builtin_amdgcn_global_load_lds((const AS1 void*)ks3, (AS3 void*)(lds + nb_ + 3072), 16, 0, 0); \
      ks0 += 131072; ks1 += 131072; ks2 += 131072; ks3 += 131072;                      \
    }                                                                                  \
    asm volatile("s_waitcnt vmcnt(" WAITK ")" ::: "memory");                           \
    __builtin_amdgcn_sched_barrier(0);                                                 \
    const int bofs = cur << 12;                                                        \
    f32x16 s = {};                                                                     \
    __builtin_amdgcn_s_setprio(1);                                                     \
    s = MFMA32(*reinterpret_cast<const short8*>(lds + aoff[0] + bofs), qf[0], s);      \
    s = MFMA32(*reinterpret_cast<const short8*>(lds + aoff[1] + bofs), qf[1], s);      \
    s = MFMA32(*reinterpret_cast<const short8*>(lds + aoff[2] + bofs), qf[2], s);      \
    s = MFMA32(*reinterpret_cast<const short8*>(lds + aoff[3] + bofs), qf[3], s);      \
    __builtin_amdgcn_s_setprio(0);                                                     \
    float p[16];                                                                       \
    _Pragma("unroll")                                                                  \
    for (int i_ = 0; i_ < 16; ++i_) {                                                  \
      p[i_] = __builtin_exp2f(s[i_]);                                                  \
      if ((i_ & 3) == 0) ls0 += p[i_]; else if ((i_ & 3) == 1) ls1 += p[i_];           \
      else if ((i_ & 3) == 2) ls2 += p[i_]; else ls3 += p[i_];                         \
    }                                                                                  \
    unsigned a0 = cvt_pk_bf16(p[0], p[1]),   a1 = cvt_pk_bf16(p[4], p[5]);             \
    unsigned b0 = cvt_pk_bf16(p[2], p[3]),   b1 = cvt_pk_bf16(p[6], p[7]);             \
    pl32_swap(a0, a1); pl32_swap(b0, b1);                                              \
    short8 pf0 = mk8(a0, b0, a1, b1);                                                  \
    unsigned c0 = cvt_pk_bf16(p[8], p[9]),   c1 = cvt_pk_bf16(p[12], p[13]);           \
    unsigned d0 = cvt_pk_bf16(p[10], p[11]), d1 = cvt_pk_bf16(p[14], p[15]);           \
    pl32_swap(c0, c1); pl32_swap(d0, d1);                                              \
    short8 pf1 = mk8(c0, d0, c1, d1);                                                  \
    __builtin_amdgcn_s_setprio(1);                                                     \
    ot0 = MFMA32(VC0, pf0, ot0);                                                       \
    ot0 = MFMA32(VC1, pf1, ot0);                                                       \
    ot1 = MFMA32(VC2, pf0, ot1);                                                       \
    ot1 = MFMA32(VC3, pf1, ot1);                                                       \
    __builtin_amdgcn_s_setprio(0);                                                     \
    cur ^= 1;                                                                          \
  }

  for (int it2 = 0; it2 < 15; ++it2) {                       // tiles 0..29
    ATTN_TILE(vfa0, vfa1, vfa2, vfa3, vfb0, vfb1, vfb2, vfb3, 1, "8");
    ATTN_TILE(vfb0, vfb1, vfb2, vfb3, vfa0, vfa1, vfa2, vfa3, 1, "8");
  }
  ATTN_TILE(vfa0, vfa1, vfa2, vfa3, vfb0, vfb1, vfb2, vfb3, 1, "8");   // tile 30
  ATTN_TILE(vfb0, vfb1, vfb2, vfb3, vfa0, vfa1, vfa2, vfa3, 0, "0");   // tile 31
#undef ATTN_TILE

  // ---- merge epilogue: O = O_w0 + O_w1, l = l_w0 + l_w1 (fixed-base -> additive) ----
  float* mbuf = (float*)lds;               // [64 d][32 q] fp32 (8 KiB)
  float* dbuf = (float*)(lds + 8192);      // [32 q]
  char*  obuf = lds + 8320;                // [32 q][64 d] bf16, q-row swizzled

  float lsum = (ls0 + ls1) + (ls2 + ls3);
  lsum += __shfl_xor(lsum, 32, 64);

  __syncthreads();   // both waves done with K bufs
  if (w == 1) {
#pragma unroll
    for (int r = 0; r < 16; ++r) {
      int d = (r & 3) + 8 * (r >> 2) + 4 * hi;
      mbuf[d * 32 + lq] = ot0[r];
      mbuf[(32 + d) * 32 + lq] = ot1[r];
    }
    if (hi == 0) dbuf[lq] = lsum;
  }
  __syncthreads();
  if (w == 0) {
    const float inv = 1.0f / (lsum + dbuf[lq]);
    const int swz = (lq & 7) << 4;
#pragma unroll
    for (int r = 0; r < 16; r += 2) {
      int d = (r & 3) + 8 * (r >> 2) + 4 * hi;
      float o0a = (ot0[r] + mbuf[d * 32 + lq]) * inv;
      float o0b = (ot0[r + 1] + mbuf[(d + 1) * 32 + lq]) * inv;
      *(unsigned*)(obuf + lq * 128 + ((2 * d) ^ swz)) = cvt_pk_bf16(o0a, o0b);
      float o1a = (ot1[r] + mbuf[(32 + d) * 32 + lq]) * inv;
      float o1b = (ot1[r + 1] + mbuf[(33 + d) * 32 + lq]) * inv;
      *(unsigned*)(obuf + lq * 128 + ((2 * (32 + d)) ^ swz)) = cvt_pk_bf16(o1a, o1b);
    }
  }
  __syncthreads();
  // coalesced store: 128 threads cover 32 rows x 128 B
  {
    int row = tid >> 2;
    int c2 = (tid & 3) * 2;
    int swzr = (row & 7) << 4;
    const char* src = obuf + row * 128;
    short8 v0 = *reinterpret_cast<const short8*>(src + ((c2 * 16) ^ swzr));
    short8 v1 = *reinterpret_cast<const short8*>(src + (((c2 + 1) * 16) ^ swzr));
    unsigned short* orow = aout + (size_t)(b * 2048 + qb * 32 + row) * 1024 + h * 64 + c2 * 8;
    *reinterpret_cast<short8*>(orow) = v0;
    *reinterpret_cast<short8*>(orow + 8) = v1;
  }
}

// ---------------- host ----------------
extern "C" void kernel_launch(void* const* d_in, const int* in_sizes, int n_in,
                              void* d_out, int out_size, void* d_ws, size_t ws_size,
                              hipStream_t stream) {
  const float* x  = (const float*)d_in[0];
  const float* wq = (const float*)d_in[1];
  const float* bq = (const float*)d_in[2];
  const float* wk = (const float*)d_in[3];
  const float* bk = (const float*)d_in[4];
  const float* wv = (const float*)d_in[5];
  const float* bv = (const float*)d_in[6];
  const float* wo = (const float*)d_in[7];
  const float* bo = (const float*)d_in[8];
  float* out = (float*)d_out;

  char* ws = (char*)d_ws;
  unsigned short* xb    = (unsigned short*)(ws);                     // 8 MiB (dead after GEMMs)
  unsigned short* aob   = (unsigned short*)(ws);                     // reuse region 0
  unsigned short* wt    = (unsigned short*)(ws + 8388608);           // 8 MiB wq|wk|wv|wo ^T
  float*          bias3 = (float*)(ws + 16777216);                   // 12 KiB
  unsigned short* qkb   = (unsigned short*)(ws + 16777216 + 16384);  // 16 MiB Q|K [4096][2048]
  unsigned short* vtb   = (unsigned short*)(ws + 33554432 + 16384);  // 8 MiB V^T [1024][4096]

  cast_x_kernel<<<4096, 256, 0, stream>>>(x, xb);
  prep_w_kernel<<<4096, 256, 0, stream>>>(wq, wk, wv, wo, wt);
  pack_bias_kernel<<<12, 256, 0, stream>>>(bq, bk, bv, bias3);

  // QK projection -> qkb [4096][2048] (Q cols pre-scaled by 0.125*log2e)
  gemm_bt_kernel<1><<<512, 256, 0, stream>>>(xb, wt, bias3, nullptr, qkb, 2048);
  // V^T projection -> vtb [1024][4096] (A = wv^T, Bt = x, row bias bv)
  gemm_bt_kernel<2><<<256, 256, 0, stream>>>(wt + (size_t)2048 * 1024, xb, bias3 + 2048,
                                             nullptr, vtb, 4096);

  // attention -> aob [4096][1024] bf16
  attn_kernel<<<2048, 128, 0, stream>>>(qkb, vtb, aob);

  // output projection -> fp32 d_out [4096][1024]
  gemm_bt_kernel<0><<<256, 256, 0, stream>>>(aob, wt + (size_t)3072 * 1024, bo, out,
                                             nullptr, 1024);
}

// Round 9
// 164.551 us; speedup vs baseline: 1.1093x; 1.1093x over previous
//
#include <hip/hip_runtime.h>
#include <stdint.h>
#include <stddef.h>

// MHA: x[2,2048,1024] -> QKV proj (bf16 MFMA) -> flash attn (H=16, Dh=64) -> out proj.
// R9: back to the measured-best R3 attn structure (4-wave blocks, K+V LDS dbuf, 64-t
//     tiles), with (a) KV-split x2 across blocks (additive fixed-base partials -> fp16
//     O-partials + fp32 l-partials + tiny merge kernel) to reach 4 waves/SIMD, and
//     (b) l-sum computed by ones-MFMA instead of 32 VALU adds/tile. GEMMs = R4 config.
//     ws guard: split=2 only if ws_size >= 51.5 MB (else split=1 fallback).

typedef __attribute__((ext_vector_type(8))) short short8;
typedef __attribute__((ext_vector_type(4))) float f32x4;
typedef __attribute__((ext_vector_type(16))) float f32x16;
typedef __attribute__((ext_vector_type(4))) unsigned short u16x4;
typedef _Float16 h4 __attribute__((ext_vector_type(4)));

#define MFMA16(a, b, c) __builtin_amdgcn_mfma_f32_16x16x32_bf16((a), (b), (c), 0, 0, 0)
#define MFMA32(a, b, c) __builtin_amdgcn_mfma_f32_32x32x16_bf16((a), (b), (c), 0, 0, 0)
#define AS1 __attribute__((address_space(1)))
#define AS3 __attribute__((address_space(3)))

__device__ __forceinline__ unsigned short f2bf(float f) {
  union { float f; unsigned u; } v; v.f = f;
  unsigned r = v.u + 0x7fffu + ((v.u >> 16) & 1u);   // RNE
  return (unsigned short)(r >> 16);
}

__device__ __forceinline__ unsigned cvt_pk_bf16(float lo, float hi) {
  unsigned r;
  asm("v_cvt_pk_bf16_f32 %0, %1, %2" : "=v"(r) : "v"(lo), "v"(hi));
  return r;
}

__device__ __forceinline__ void pl32_swap(unsigned& a, unsigned& b) {
  asm volatile("v_permlane32_swap_b32 %0, %1" : "+v"(a), "+v"(b));
}

__device__ __forceinline__ short8 mk8(unsigned a, unsigned b, unsigned c, unsigned d) {
  union { unsigned u[4]; short8 s; } v;
  v.u[0] = a; v.u[1] = b; v.u[2] = c; v.u[3] = d;
  return v.s;
}

// ---------------- prep ----------------
__global__ __launch_bounds__(256) void cast_x_kernel(const float* __restrict__ x,
                                                     unsigned short* __restrict__ xb) {
  int i = (blockIdx.x * 256 + threadIdx.x) * 4;
  float4 v = *reinterpret_cast<const float4*>(x + i);
  u16x4 o;
  o.x = f2bf(v.x); o.y = f2bf(v.y); o.z = f2bf(v.z); o.w = f2bf(v.w);
  *reinterpret_cast<u16x4*>(xb + i) = o;
}

__global__ __launch_bounds__(256) void prep_w_kernel(const float* __restrict__ wq,
                                                     const float* __restrict__ wk,
                                                     const float* __restrict__ wv,
                                                     const float* __restrict__ wo,
                                                     unsigned short* __restrict__ wt) {
  __shared__ unsigned short t_lds[32][33];
  int bid = blockIdx.x;
  int wsel = bid >> 10;
  int rem = bid & 1023;
  int kb = (rem >> 5) << 5;
  int nb = (rem & 31) << 5;
  const float* W = (wsel == 0) ? wq : (wsel == 1) ? wk : (wsel == 2) ? wv : wo;
  int t = threadIdx.x;
  int r = t >> 3, c = (t & 7) * 4;
  float4 v = *reinterpret_cast<const float4*>(W + (size_t)(kb + r) * 1024 + nb + c);
  t_lds[r][c + 0] = f2bf(v.x);
  t_lds[r][c + 1] = f2bf(v.y);
  t_lds[r][c + 2] = f2bf(v.z);
  t_lds[r][c + 3] = f2bf(v.w);
  __syncthreads();
  u16x4 o;
  o.x = t_lds[c + 0][r]; o.y = t_lds[c + 1][r];
  o.z = t_lds[c + 2][r]; o.w = t_lds[c + 3][r];
  *reinterpret_cast<u16x4*>(wt + (size_t)(wsel * 1024 + nb + r) * 1024 + kb + c) = o;
}

__global__ __launch_bounds__(256) void pack_bias_kernel(const float* __restrict__ bq,
                                                        const float* __restrict__ bk,
                                                        const float* __restrict__ bv,
                                                        float* __restrict__ bias3) {
  int i = blockIdx.x * 256 + threadIdx.x;
  if (i < 3072) bias3[i] = (i < 1024) ? bq[i] : (i < 2048) ? bk[i - 1024] : bv[i - 2048];
}

// ---------------- GEMM (R4 config): 2-phase dbuf, single barrier per K-step ----------------
template <typename OutT, bool QS>
__global__ __launch_bounds__(256) void gemm_bt_kernel(const unsigned short* __restrict__ A,
                                                      const unsigned short* __restrict__ Bt,
                                                      const float* __restrict__ bias,
                                                      OutT* __restrict__ C, int N) {
  constexpr int K = 1024;
  __shared__ __align__(16) unsigned short a_lds[2][128 * 32];
  __shared__ __align__(16) unsigned short b_lds[2][128 * 32];
  const int nb = N >> 7;
  const int nwg = nb << 5;
  const int cpx = nwg >> 3;
  const int wg = ((int)blockIdx.x & 7) * cpx + ((int)blockIdx.x >> 3);  // XCD swizzle
  const int bm = wg / nb;
  const int bn = wg % nb;
  const int m0 = bm << 7, n0 = bn << 7;
  const int tid = threadIdx.x;
  const int w = tid >> 6, l = tid & 63;
  const int lr = l & 15, lg = l >> 4;
  const int wm = (w >> 1) << 6, wn = (w & 1) << 6;

  const int q0 = w * 2, q1 = w * 2 + 1;
  const unsigned short* pa0 = A + (size_t)(m0 + q0 * 16 + (l >> 2)) * K + (l & 3) * 8;
  const unsigned short* pa1 = A + (size_t)(m0 + q1 * 16 + (l >> 2)) * K + (l & 3) * 8;
  const unsigned short* pb0 = Bt + (size_t)(n0 + q0 * 16 + (l >> 2)) * K + (l & 3) * 8;
  const unsigned short* pb1 = Bt + (size_t)(n0 + q1 * 16 + (l >> 2)) * K + (l & 3) * 8;

#define GEMM_STAGE(buf, k0)                                                        \
  do {                                                                             \
    __builtin_amdgcn_global_load_lds((const AS1 void*)(pa0 + (k0)),                \
        (AS3 void*)(&a_lds[buf][q0 * 512]), 16, 0, 0);                             \
    __builtin_amdgcn_global_load_lds((const AS1 void*)(pa1 + (k0)),                \
        (AS3 void*)(&a_lds[buf][q1 * 512]), 16, 0, 0);                             \
    __builtin_amdgcn_global_load_lds((const AS1 void*)(pb0 + (k0)),                \
        (AS3 void*)(&b_lds[buf][q0 * 512]), 16, 0, 0);                             \
    __builtin_amdgcn_global_load_lds((const AS1 void*)(pb1 + (k0)),                \
        (AS3 void*)(&b_lds[buf][q1 * 512]), 16, 0, 0);                             \
  } while (0)

  f32x4 acc[4][4] = {};
  GEMM_STAGE(0, 0);
  __syncthreads();

  int cur = 0;
  for (int k0 = 0; k0 < K; k0 += 32) {
    if (k0 + 32 < K) GEMM_STAGE(cur ^ 1, k0 + 32);
    short8 af[4], bfr[4];
#pragma unroll
    for (int i = 0; i < 4; ++i)
      af[i] = *reinterpret_cast<const short8*>(&a_lds[cur][(wm + i * 16 + lr) * 32 + lg * 8]);
#pragma unroll
    for (int i = 0; i < 4; ++i)
      bfr[i] = *reinterpret_cast<const short8*>(&b_lds[cur][(wn + i * 16 + lr) * 32 + lg * 8]);
#pragma unroll
    for (int i = 0; i < 4; ++i)
#pragma unroll
      for (int j = 0; j < 4; ++j)
        acc[i][j] = MFMA16(af[i], bfr[j], acc[i][j]);
    __syncthreads();
    cur ^= 1;
  }
#undef GEMM_STAGE

  const float scale = (QS && n0 < 1024) ? 0.18033688011111f : 1.0f;  // 0.125*log2e
#pragma unroll
  for (int i = 0; i < 4; ++i) {
#pragma unroll
    for (int j = 0; j < 4; ++j) {
#pragma unroll
      for (int r = 0; r < 4; ++r) {
        int m = m0 + wm + i * 16 + lg * 4 + r;
        int n = n0 + wn + j * 16 + lr;
        float val = (acc[i][j][r] + bias[n]) * scale;
        if constexpr (sizeof(OutT) == 2) {
          C[(size_t)m * N + n] = (OutT)f2bf(val);
        } else {
          C[(size_t)m * N + n] = val;
        }
      }
    }
  }
}

// ---------------- flash attention (R3 structure + kv-split + ones-MFMA l) ----------------
__device__ __forceinline__ void stage_kv(char* kw, char* vw, int ktt, int kd0, int pi, int vd0,
                                         short8 k0, short8 k1, short8 va, short8 vb) {
  *reinterpret_cast<short8*>(kw + ktt * 128 + ((kd0 * 2) ^ ((ktt & 7) << 4))) = k0;
  *reinterpret_cast<short8*>(kw + (ktt + 32) * 128 + ((kd0 * 2) ^ ((ktt & 7) << 4))) = k1;
  union { short8 s; unsigned u[4]; } ua, ub;
  ua.s = va; ub.s = vb;
#pragma unroll
  for (int jr = 0; jr < 4; ++jr) {
    unsigned w0 = __builtin_amdgcn_perm(ub.u[jr], ua.u[jr], 0x05040100u);  // lo halves
    unsigned w1 = __builtin_amdgcn_perm(ub.u[jr], ua.u[jr], 0x07060302u);  // hi halves
    int d0 = vd0 + 2 * jr, d1 = d0 + 1;
    *reinterpret_cast<unsigned*>(vw + d0 * 128 + ((4 * pi) ^ ((d0 & 7) << 4))) = w0;
    *reinterpret_cast<unsigned*>(vw + d1 * 128 + ((4 * pi) ^ ((d1 & 7) << 4))) = w1;
  }
}

// grid 512*S: (b,h)[32] x qblk[16] x kv[S]; 4 waves x 32 q rows; each block covers
// t in [kv*2048/S, +2048/S) in 64-t tiles. Fixed-base softmax (p = exp2(s), Q pre-scaled
// into log2 domain); l via ones-MFMA; fp16 O^T partials + fp32 l partials to ws.
template <int S>
__global__ __launch_bounds__(256, 4) void attn_kernel(const unsigned short* __restrict__ qkv,
                                                      _Float16* __restrict__ poA,
                                                      _Float16* __restrict__ poB,
                                                      float* __restrict__ pl) {
  constexpr int TLEN = 2048 / S;
  __shared__ __align__(16) unsigned short k_lds[2][64 * 64];   // [t][d] swizzled, dbuf
  __shared__ __align__(16) unsigned short vt_lds[2][64 * 64];  // [d][t] swizzled, dbuf
  const int tid = threadIdx.x;
  const int w = tid >> 6, l = tid & 63;
  const int lq = l & 31;
  const int hi = l >> 5;
  const int nwg = 512 * S;
  const int wg = ((int)blockIdx.x & 7) * (nwg >> 3) + ((int)blockIdx.x >> 3);  // XCD swizzle
  int bh, qblk, kv;
  if (S == 2) { bh = wg >> 5; qblk = (wg >> 1) & 15; kv = wg & 1; }
  else        { bh = wg >> 4; qblk = wg & 15;        kv = 0; }
  const int b = bh >> 4, h = bh & 15;
  const size_t rowbase = (size_t)b * 2048;
  const int q0 = qblk * 128 + w * 32;

  // Q fragments (B-operand); Q pre-scaled by 0.125*log2e in GEMM epilogue.
  short8 qf[4];
  {
    const unsigned short* qrow = qkv + (rowbase + q0 + lq) * 3072 + h * 64 + hi * 8;
#pragma unroll
    for (int c = 0; c < 4; ++c)
      qf[c] = *reinterpret_cast<const short8*>(qrow + c * 16);
  }

  const unsigned short* kbase = qkv + (rowbase + kv * TLEN) * 3072 + 1024 + h * 64;
  const unsigned short* vbase = qkv + (rowbase + kv * TLEN) * 3072 + 2048 + h * 64;

  const int ktt = tid >> 3;            // K stage row (+32 for rep)
  const int kd0 = (tid & 7) * 8;       // K stage d chunk
  const int pi = tid & 31;             // V stage t-pair index
  const int vd0 = (tid >> 5) * 8;      // V stage d chunk
  const int swz_lq = (lq & 7) << 4;

  short8 ones;                          // bf16 1.0 x8 (A-operand for l-sum MFMA)
  {
    union { unsigned u[4]; short8 s; } o_;
    o_.u[0] = o_.u[1] = o_.u[2] = o_.u[3] = 0x3F803F80u;
    ones = o_.s;
  }

  f32x16 ot0 = {}, ot1 = {}, lacc = {};

  // prologue: stage tile 0 into buf 0
  short8 kpre0 = *reinterpret_cast<const short8*>(kbase + (size_t)ktt * 3072 + kd0);
  short8 kpre1 = *reinterpret_cast<const short8*>(kbase + (size_t)(ktt + 32) * 3072 + kd0);
  short8 vpa = *reinterpret_cast<const short8*>(vbase + (size_t)(2 * pi) * 3072 + vd0);
  short8 vpb = *reinterpret_cast<const short8*>(vbase + (size_t)(2 * pi + 1) * 3072 + vd0);
  stage_kv((char*)k_lds[0], (char*)vt_lds[0], ktt, kd0, pi, vd0, kpre0, kpre1, vpa, vpb);

  int cur = 0;
  for (int t0 = 0; t0 < TLEN; t0 += 64) {
    __syncthreads();   // buf[cur] staged; buf[cur^1] readers from prev iter done
    const bool more = (t0 + 64) < TLEN;
    if (more) {   // issue next-tile loads early; latency hides under QK^T
      kpre0 = *reinterpret_cast<const short8*>(kbase + (size_t)(t0 + 64 + ktt) * 3072 + kd0);
      kpre1 = *reinterpret_cast<const short8*>(kbase + (size_t)(t0 + 96 + ktt) * 3072 + kd0);
      vpa = *reinterpret_cast<const short8*>(vbase + (size_t)(t0 + 64 + 2 * pi) * 3072 + vd0);
      vpb = *reinterpret_cast<const short8*>(vbase + (size_t)(t0 + 65 + 2 * pi) * 3072 + vd0);
    }
    const char* kl = (const char*)k_lds[cur];
    const char* vl = (const char*)vt_lds[cur];

    // --- QK^T (swapped): lane owns S^T[.][q=lq] ---
    f32x16 s0 = {}, s1 = {};
    __builtin_amdgcn_s_setprio(1);
#pragma unroll
    for (int c = 0; c < 4; ++c) {
      short8 kf0 = *reinterpret_cast<const short8*>(kl + lq * 128 + ((c * 32 + hi * 16) ^ swz_lq));
      short8 kf1 = *reinterpret_cast<const short8*>(kl + (32 + lq) * 128 + ((c * 32 + hi * 16) ^ swz_lq));
      s0 = MFMA32(kf0, qf[c], s0);
      s1 = MFMA32(kf1, qf[c], s1);
    }
    __builtin_amdgcn_s_setprio(0);

    // stage next tile into the other buffer (overlaps with softmax+PV)
    if (more)
      stage_kv((char*)k_lds[cur ^ 1], (char*)vt_lds[cur ^ 1], ktt, kd0, pi, vd0,
               kpre0, kpre1, vpa, vpb);

    // --- softmax-lite: p = exp2(s); NO VALU sums (l comes from ones-MFMA) ---
    float p0[16], p1[16];
#pragma unroll
    for (int i = 0; i < 16; ++i) p0[i] = __builtin_exp2f(s0[i]);
#pragma unroll
    for (int i = 0; i < 16; ++i) p1[i] = __builtin_exp2f(s1[i]);

    // --- P -> bf16 B-fragments (cvt_pk + permlane32_swap) ---
    short8 pf[4];
    {
      unsigned a0 = cvt_pk_bf16(p0[0], p0[1]),   a1 = cvt_pk_bf16(p0[4], p0[5]);
      unsigned b0 = cvt_pk_bf16(p0[2], p0[3]),   b1 = cvt_pk_bf16(p0[6], p0[7]);
      pl32_swap(a0, a1); pl32_swap(b0, b1);
      pf[0] = mk8(a0, b0, a1, b1);
      unsigned c0 = cvt_pk_bf16(p0[8], p0[9]),   c1 = cvt_pk_bf16(p0[12], p0[13]);
      unsigned d0 = cvt_pk_bf16(p0[10], p0[11]), d1 = cvt_pk_bf16(p0[14], p0[15]);
      pl32_swap(c0, c1); pl32_swap(d0, d1);
      pf[1] = mk8(c0, d0, c1, d1);
      unsigned e0 = cvt_pk_bf16(p1[0], p1[1]),   e1 = cvt_pk_bf16(p1[4], p1[5]);
      unsigned f0 = cvt_pk_bf16(p1[2], p1[3]),   f1 = cvt_pk_bf16(p1[6], p1[7]);
      pl32_swap(e0, e1); pl32_swap(f0, f1);
      pf[2] = mk8(e0, f0, e1, f1);
      unsigned g0 = cvt_pk_bf16(p1[8], p1[9]),   g1 = cvt_pk_bf16(p1[12], p1[13]);
      unsigned h0 = cvt_pk_bf16(p1[10], p1[11]), h1 = cvt_pk_bf16(p1[14], p1[15]);
      pl32_swap(g0, g1); pl32_swap(h0, h1);
      pf[3] = mk8(g0, h0, g1, h1);
    }

    // --- PV + l: ot += mfma(V^T, P); lacc += mfma(ones, P) (every row = sum_t P) ---
    __builtin_amdgcn_s_setprio(1);
#pragma unroll
    for (int c = 0; c < 4; ++c) {
      short8 vf0 = *reinterpret_cast<const short8*>(vl + lq * 128 + ((c * 32 + hi * 16) ^ swz_lq));
      short8 vf1 = *reinterpret_cast<const short8*>(vl + (32 + lq) * 128 + ((c * 32 + hi * 16) ^ swz_lq));
      ot0 = MFMA32(vf0, pf[c], ot0);
      ot1 = MFMA32(vf1, pf[c], ot1);
      lacc = MFMA32(ones, pf[c], lacc);
    }
    __builtin_amdgcn_s_setprio(0);
    cur ^= 1;
  }

  // ---- epilogue: store fp16 O^T partial [64 d][128 q] + fp32 l partial ----
  const int g = bh * 16 + qblk;
  _Float16* pop = (kv == 0 ? poA : poB) + (size_t)g * 8192;
#pragma unroll
  for (int r = 0; r < 16; ++r) {
    int d = (r & 3) + 8 * (r >> 2) + 4 * hi;
    pop[d * 128 + w * 32 + lq] = (_Float16)ot0[r];
    pop[(32 + d) * 128 + w * 32 + lq] = (_Float16)ot1[r];
  }
  if (hi == 0) pl[(size_t)(g * S + kv) * 128 + w * 32 + lq] = lacc[0];
}

// ---------------- merge: O = (P0 + P1) / (l0 + l1), transpose to row-major bf16 ----------------
template <int S>
__global__ __launch_bounds__(256) void merge_kernel(const _Float16* __restrict__ poA,
                                                    const _Float16* __restrict__ poB,
                                                    const float* __restrict__ pl,
                                                    unsigned short* __restrict__ aout) {
  __shared__ unsigned short lo[128][72];
  const int g = blockIdx.x;                 // 512 = (bh, qblk)
  const int bh = g >> 4, qblk = g & 15;
  const int b = bh >> 4, h = bh & 15;
  const int tid = threadIdx.x;
  const int qi = (tid & 31) * 4;
  const int dg = tid >> 5;
  const _Float16* P0 = poA + (size_t)g * 8192;
  const _Float16* P1 = poB + (size_t)g * 8192;
  const float* L = pl + (size_t)g * S * 128;

  float inv[4];
#pragma unroll
  for (int j = 0; j < 4; ++j) {
    float lv = L[qi + j];
    if (S == 2) lv += L[128 + qi + j];
    inv[j] = 1.0f / lv;
  }
#pragma unroll
  for (int dd = 0; dd < 8; ++dd) {
    int d = dg * 8 + dd;
    h4 a = *reinterpret_cast<const h4*>(P0 + d * 128 + qi);
    float o[4];
#pragma unroll
    for (int j = 0; j < 4; ++j) o[j] = (float)a[j];
    if (S == 2) {
      h4 bb = *reinterpret_cast<const h4*>(P1 + d * 128 + qi);
#pragma unroll
      for (int j = 0; j < 4; ++j) o[j] += (float)bb[j];
    }
#pragma unroll
    for (int j = 0; j < 4; ++j) lo[qi + j][d] = f2bf(o[j] * inv[j]);
  }
  __syncthreads();
  const int q = tid >> 1, c0 = (tid & 1) * 32;
  unsigned short* orow = aout + (size_t)(b * 2048 + qblk * 128 + q) * 1024 + h * 64 + c0;
#pragma unroll
  for (int k = 0; k < 4; ++k)
    *reinterpret_cast<short8*>(orow + k * 8) =
        *reinterpret_cast<const short8*>(&lo[q][c0 + k * 8]);
}

// ---------------- host ----------------
extern "C" void kernel_launch(void* const* d_in, const int* in_sizes, int n_in,
                              void* d_out, int out_size, void* d_ws, size_t ws_size,
                              hipStream_t stream) {
  const float* x  = (const float*)d_in[0];
  const float* wq = (const float*)d_in[1];
  const float* bq = (const float*)d_in[2];
  const float* wk = (const float*)d_in[3];
  const float* bk = (const float*)d_in[4];
  const float* wv = (const float*)d_in[5];
  const float* bv = (const float*)d_in[6];
  const float* wo = (const float*)d_in[7];
  const float* bo = (const float*)d_in[8];
  float* out = (float*)d_out;

  char* ws = (char*)d_ws;
  // layout (bytes):
  //   [0, 8M):        xb during GEMMs; poA during attn/merge
  //   [8M, 16M):      wt (wo^T needed until out-proj)
  //   [16M, +12K):    bias3
  //   [16M+64K, +24M):qkvb during attn; aob (8 MB) during merge/out-proj (qkvb dead)
  //   [42.01M, +8M):  poB            (split=2 only)
  //   pl: split=2 -> 50.40M, split=1 -> 42.01M
  unsigned short* xb    = (unsigned short*)(ws);
  _Float16*       poA   = (_Float16*)(ws);
  unsigned short* wt    = (unsigned short*)(ws + 8388608);
  float*          bias3 = (float*)(ws + 16777216);
  unsigned short* qkvb  = (unsigned short*)(ws + 16842752);
  unsigned short* aob   = qkvb;
  _Float16*       poB   = (_Float16*)(ws + 42008576);
  const bool s2 = ws_size >= (size_t)51500000;
  float* pl = (float*)(s2 ? (ws + 50397184) : (ws + 42008576));

  cast_x_kernel<<<4096, 256, 0, stream>>>(x, xb);
  prep_w_kernel<<<4096, 256, 0, stream>>>(wq, wk, wv, wo, wt);
  pack_bias_kernel<<<12, 256, 0, stream>>>(bq, bk, bv, bias3);

  // fused QKV projection (Q pre-scaled by 0.125*log2e): [4096][3072] bf16
  gemm_bt_kernel<unsigned short, true><<<768, 256, 0, stream>>>(xb, wt, bias3, qkvb, 3072);

  // attention partials + merge -> aob [4096][1024] bf16
  if (s2) {
    attn_kernel<2><<<1024, 256, 0, stream>>>(qkvb, poA, poB, pl);
    merge_kernel<2><<<512, 256, 0, stream>>>(poA, poB, pl, aob);
  } else {
    attn_kernel<1><<<512, 256, 0, stream>>>(qkvb, poA, poB, pl);
    merge_kernel<1><<<512, 256, 0, stream>>>(poA, poB, pl, aob);
  }

  // output projection -> fp32 d_out [4096][1024]
  gemm_bt_kernel<float, false><<<256, 256, 0, stream>>>(aob, wt + (size_t)3072 * 1024, bo, out, 1024);
}

// Round 10
// 139.021 us; speedup vs baseline: 1.3130x; 1.1836x over previous
//
#include <hip/hip_runtime.h>
#include <stdint.h>
#include <stddef.h>

// MHA: x[2,2048,1024] -> QKV proj (bf16 MFMA) -> flash attn (H=16, Dh=64) -> out proj.
// R10: R9 (kv-split x2 + fp16 partials + merge) register-budgeted to fit 4 waves/SIMD
//      WITHOUT spill (R9 spilled: VGPR capped 64, 152 MB scratch writes):
//      - no ones-MFMA (scalar l sums, -16 AGPR)
//      - fused per-quadrant softmax->pf->PV (live p 32->8, pf 16->4)
//      - K via global_load_lds w/ pre-swizzled source (frees K prefetch regs)

typedef __attribute__((ext_vector_type(8))) short short8;
typedef __attribute__((ext_vector_type(4))) float f32x4;
typedef __attribute__((ext_vector_type(16))) float f32x16;
typedef __attribute__((ext_vector_type(4))) unsigned short u16x4;
typedef _Float16 h4 __attribute__((ext_vector_type(4)));

#define MFMA16(a, b, c) __builtin_amdgcn_mfma_f32_16x16x32_bf16((a), (b), (c), 0, 0, 0)
#define MFMA32(a, b, c) __builtin_amdgcn_mfma_f32_32x32x16_bf16((a), (b), (c), 0, 0, 0)
#define AS1 __attribute__((address_space(1)))
#define AS3 __attribute__((address_space(3)))

__device__ __forceinline__ unsigned short f2bf(float f) {
  union { float f; unsigned u; } v; v.f = f;
  unsigned r = v.u + 0x7fffu + ((v.u >> 16) & 1u);   // RNE
  return (unsigned short)(r >> 16);
}

__device__ __forceinline__ unsigned cvt_pk_bf16(float lo, float hi) {
  unsigned r;
  asm("v_cvt_pk_bf16_f32 %0, %1, %2" : "=v"(r) : "v"(lo), "v"(hi));
  return r;
}

__device__ __forceinline__ void pl32_swap(unsigned& a, unsigned& b) {
  asm volatile("v_permlane32_swap_b32 %0, %1" : "+v"(a), "+v"(b));
}

__device__ __forceinline__ short8 mk8(unsigned a, unsigned b, unsigned c, unsigned d) {
  union { unsigned u[4]; short8 s; } v;
  v.u[0] = a; v.u[1] = b; v.u[2] = c; v.u[3] = d;
  return v.s;
}

// ---------------- prep ----------------
__global__ __launch_bounds__(256) void cast_x_kernel(const float* __restrict__ x,
                                                     unsigned short* __restrict__ xb) {
  int i = (blockIdx.x * 256 + threadIdx.x) * 4;
  float4 v = *reinterpret_cast<const float4*>(x + i);
  u16x4 o;
  o.x = f2bf(v.x); o.y = f2bf(v.y); o.z = f2bf(v.z); o.w = f2bf(v.w);
  *reinterpret_cast<u16x4*>(xb + i) = o;
}

__global__ __launch_bounds__(256) void prep_w_kernel(const float* __restrict__ wq,
                                                     const float* __restrict__ wk,
                                                     const float* __restrict__ wv,
                                                     const float* __restrict__ wo,
                                                     unsigned short* __restrict__ wt) {
  __shared__ unsigned short t_lds[32][33];
  int bid = blockIdx.x;
  int wsel = bid >> 10;
  int rem = bid & 1023;
  int kb = (rem >> 5) << 5;
  int nb = (rem & 31) << 5;
  const float* W = (wsel == 0) ? wq : (wsel == 1) ? wk : (wsel == 2) ? wv : wo;
  int t = threadIdx.x;
  int r = t >> 3, c = (t & 7) * 4;
  float4 v = *reinterpret_cast<const float4*>(W + (size_t)(kb + r) * 1024 + nb + c);
  t_lds[r][c + 0] = f2bf(v.x);
  t_lds[r][c + 1] = f2bf(v.y);
  t_lds[r][c + 2] = f2bf(v.z);
  t_lds[r][c + 3] = f2bf(v.w);
  __syncthreads();
  u16x4 o;
  o.x = t_lds[c + 0][r]; o.y = t_lds[c + 1][r];
  o.z = t_lds[c + 2][r]; o.w = t_lds[c + 3][r];
  *reinterpret_cast<u16x4*>(wt + (size_t)(wsel * 1024 + nb + r) * 1024 + kb + c) = o;
}

__global__ __launch_bounds__(256) void pack_bias_kernel(const float* __restrict__ bq,
                                                        const float* __restrict__ bk,
                                                        const float* __restrict__ bv,
                                                        float* __restrict__ bias3) {
  int i = blockIdx.x * 256 + threadIdx.x;
  if (i < 3072) bias3[i] = (i < 1024) ? bq[i] : (i < 2048) ? bk[i - 1024] : bv[i - 2048];
}

// ---------------- GEMM (R4 config): 2-phase dbuf, single barrier per K-step ----------------
template <typename OutT, bool QS>
__global__ __launch_bounds__(256) void gemm_bt_kernel(const unsigned short* __restrict__ A,
                                                      const unsigned short* __restrict__ Bt,
                                                      const float* __restrict__ bias,
                                                      OutT* __restrict__ C, int N) {
  constexpr int K = 1024;
  __shared__ __align__(16) unsigned short a_lds[2][128 * 32];
  __shared__ __align__(16) unsigned short b_lds[2][128 * 32];
  const int nb = N >> 7;
  const int nwg = nb << 5;
  const int cpx = nwg >> 3;
  const int wg = ((int)blockIdx.x & 7) * cpx + ((int)blockIdx.x >> 3);  // XCD swizzle
  const int bm = wg / nb;
  const int bn = wg % nb;
  const int m0 = bm << 7, n0 = bn << 7;
  const int tid = threadIdx.x;
  const int w = tid >> 6, l = tid & 63;
  const int lr = l & 15, lg = l >> 4;
  const int wm = (w >> 1) << 6, wn = (w & 1) << 6;

  const int q0 = w * 2, q1 = w * 2 + 1;
  const unsigned short* pa0 = A + (size_t)(m0 + q0 * 16 + (l >> 2)) * K + (l & 3) * 8;
  const unsigned short* pa1 = A + (size_t)(m0 + q1 * 16 + (l >> 2)) * K + (l & 3) * 8;
  const unsigned short* pb0 = Bt + (size_t)(n0 + q0 * 16 + (l >> 2)) * K + (l & 3) * 8;
  const unsigned short* pb1 = Bt + (size_t)(n0 + q1 * 16 + (l >> 2)) * K + (l & 3) * 8;

#define GEMM_STAGE(buf, k0)                                                        \
  do {                                                                             \
    __builtin_amdgcn_global_load_lds((const AS1 void*)(pa0 + (k0)),                \
        (AS3 void*)(&a_lds[buf][q0 * 512]), 16, 0, 0);                             \
    __builtin_amdgcn_global_load_lds((const AS1 void*)(pa1 + (k0)),                \
        (AS3 void*)(&a_lds[buf][q1 * 512]), 16, 0, 0);                             \
    __builtin_amdgcn_global_load_lds((const AS1 void*)(pb0 + (k0)),                \
        (AS3 void*)(&b_lds[buf][q0 * 512]), 16, 0, 0);                             \
    __builtin_amdgcn_global_load_lds((const AS1 void*)(pb1 + (k0)),                \
        (AS3 void*)(&b_lds[buf][q1 * 512]), 16, 0, 0);                             \
  } while (0)

  f32x4 acc[4][4] = {};
  GEMM_STAGE(0, 0);
  __syncthreads();

  int cur = 0;
  for (int k0 = 0; k0 < K; k0 += 32) {
    if (k0 + 32 < K) GEMM_STAGE(cur ^ 1, k0 + 32);
    short8 af[4], bfr[4];
#pragma unroll
    for (int i = 0; i < 4; ++i)
      af[i] = *reinterpret_cast<const short8*>(&a_lds[cur][(wm + i * 16 + lr) * 32 + lg * 8]);
#pragma unroll
    for (int i = 0; i < 4; ++i)
      bfr[i] = *reinterpret_cast<const short8*>(&b_lds[cur][(wn + i * 16 + lr) * 32 + lg * 8]);
#pragma unroll
    for (int i = 0; i < 4; ++i)
#pragma unroll
      for (int j = 0; j < 4; ++j)
        acc[i][j] = MFMA16(af[i], bfr[j], acc[i][j]);
    __syncthreads();
    cur ^= 1;
  }
#undef GEMM_STAGE

  const float scale = (QS && n0 < 1024) ? 0.18033688011111f : 1.0f;  // 0.125*log2e
#pragma unroll
  for (int i = 0; i < 4; ++i) {
#pragma unroll
    for (int j = 0; j < 4; ++j) {
#pragma unroll
      for (int r = 0; r < 4; ++r) {
        int m = m0 + wm + i * 16 + lg * 4 + r;
        int n = n0 + wn + j * 16 + lr;
        float val = (acc[i][j][r] + bias[n]) * scale;
        if constexpr (sizeof(OutT) == 2) {
          C[(size_t)m * N + n] = (OutT)f2bf(val);
        } else {
          C[(size_t)m * N + n] = val;
        }
      }
    }
  }
}

// ---------------- flash attention ----------------
__device__ __forceinline__ void stage_v(char* vw, int pi, int vd0, short8 va, short8 vb) {
  union { short8 s; unsigned u[4]; } ua, ub;
  ua.s = va; ub.s = vb;
#pragma unroll
  for (int jr = 0; jr < 4; ++jr) {
    unsigned w0 = __builtin_amdgcn_perm(ub.u[jr], ua.u[jr], 0x05040100u);  // lo halves
    unsigned w1 = __builtin_amdgcn_perm(ub.u[jr], ua.u[jr], 0x07060302u);  // hi halves
    int d0 = vd0 + 2 * jr, d1 = d0 + 1;
    *reinterpret_cast<unsigned*>(vw + d0 * 128 + ((4 * pi) ^ ((d0 & 7) << 4))) = w0;
    *reinterpret_cast<unsigned*>(vw + d1 * 128 + ((4 * pi) ^ ((d1 & 7) << 4))) = w1;
  }
}

// grid 512*S: (b,h)[32] x qblk[16] x kv[S]; 4 waves x 32 q rows; block covers
// t in [kv*2048/S, +2048/S) in 64-t tiles. Fixed-base softmax (p = exp2(s), Q pre-scaled
// into log2 domain); fp16 O^T partials + fp32 l partials to ws; merge kernel normalizes.
template <int S>
__global__ __launch_bounds__(256, 4) void attn_kernel(const unsigned short* __restrict__ qkv,
                                                      _Float16* __restrict__ poA,
                                                      _Float16* __restrict__ poB,
                                                      float* __restrict__ pl) {
  constexpr int TLEN = 2048 / S;
  __shared__ __align__(16) unsigned short k_lds[2][64 * 64];   // [t][d] swizzled, dbuf
  __shared__ __align__(16) unsigned short vt_lds[2][64 * 64];  // [d][t] swizzled, dbuf
  const int tid = threadIdx.x;
  const int w = tid >> 6, l = tid & 63;
  const int lq = l & 31;
  const int hi = l >> 5;
  const int nwg = 512 * S;
  const int wg = ((int)blockIdx.x & 7) * (nwg >> 3) + ((int)blockIdx.x >> 3);  // XCD swizzle
  int bh, qblk, kv;
  if (S == 2) { bh = wg >> 5; qblk = (wg >> 1) & 15; kv = wg & 1; }
  else        { bh = wg >> 4; qblk = wg & 15;        kv = 0; }
  const int b = bh >> 4, h = bh & 15;
  const size_t rowbase = (size_t)b * 2048;
  const int q0 = qblk * 128 + w * 32;

  // Q fragments (B-operand); Q pre-scaled by 0.125*log2e in GEMM epilogue.
  short8 qf[4];
  {
    const unsigned short* qrow = qkv + (rowbase + q0 + lq) * 3072 + h * 64 + hi * 8;
#pragma unroll
    for (int c = 0; c < 4; ++c)
      qf[c] = *reinterpret_cast<const short8*>(qrow + c * 16);
  }

  // K staging via global_load_lds, pre-swizzled source (R7-verified formula).
  // Plane [64 t][128 B], swizzle (t&7)<<4. Wave w stages chunks {2w,2w+1}:
  // rows 16w+(l>>3) and +8; lane col bytes = 16(l&7) ^ ((l>>3)<<4).
  const int colsw = (16 * (l & 7)) ^ ((l >> 3) << 4);
  const char* ksrc = (const char*)(qkv + (rowbase + kv * TLEN) * 3072 + 1024 + h * 64) +
                     (size_t)(16 * w + (l >> 3)) * 6144 + colsw;
  const int kdst = w * 2048;                  // wave-uniform byte offset in 8 KB plane

  // V staging (reg + perm): lane covers t = {2pi, 2pi+1}, d = vd0..vd0+7.
  const int pi = tid & 31;
  const int vd0 = (tid >> 5) * 8;
  const unsigned short* vbase = qkv + (rowbase + kv * TLEN) * 3072 + 2048 + h * 64;
  const int swz_lq = (lq & 7) << 4;

  float ls0 = 0.f, ls1 = 0.f, ls2 = 0.f, ls3 = 0.f;
  f32x16 ot0 = {}, ot1 = {};

  // prologue: stage tile 0 into buf 0
  __builtin_amdgcn_global_load_lds((const AS1 void*)ksrc,
                                   (AS3 void*)((char*)k_lds[0] + kdst), 16, 0, 0);
  __builtin_amdgcn_global_load_lds((const AS1 void*)(ksrc + 49152),
                                   (AS3 void*)((char*)k_lds[0] + kdst + 1024), 16, 0, 0);
  ksrc += 393216;
  {
    short8 va = *reinterpret_cast<const short8*>(vbase + (size_t)(2 * pi) * 3072 + vd0);
    short8 vb = *reinterpret_cast<const short8*>(vbase + (size_t)(2 * pi + 1) * 3072 + vd0);
    stage_v((char*)vt_lds[0], pi, vd0, va, vb);
  }

  int cur = 0;
  for (int t0 = 0; t0 < TLEN; t0 += 64) {
    __syncthreads();   // drains K gll + V ds_writes into buf[cur]; prev readers done
    const bool more = (t0 + 64) < TLEN;
    short8 vna, vnb;
    if (more) {
      // next K straight to LDS buf^1 (no regs); next V to regs
      char* kd = (char*)k_lds[cur ^ 1] + kdst;
      __builtin_amdgcn_global_load_lds((const AS1 void*)ksrc, (AS3 void*)kd, 16, 0, 0);
      __builtin_amdgcn_global_load_lds((const AS1 void*)(ksrc + 49152),
                                       (AS3 void*)(kd + 1024), 16, 0, 0);
      ksrc += 393216;
      vna = *reinterpret_cast<const short8*>(vbase + (size_t)(t0 + 64 + 2 * pi) * 3072 + vd0);
      vnb = *reinterpret_cast<const short8*>(vbase + (size_t)(t0 + 65 + 2 * pi) * 3072 + vd0);
    }
    const char* kl = (const char*)k_lds[cur];
    const char* vl = (const char*)vt_lds[cur];

    // --- QK^T (swapped): lane owns S^T[.][q=lq] ---
    f32x16 s0 = {}, s1 = {};
    __builtin_amdgcn_s_setprio(1);
#pragma unroll
    for (int c = 0; c < 4; ++c) {
      short8 kf0 = *reinterpret_cast<const short8*>(kl + lq * 128 + ((c * 32 + hi * 16) ^ swz_lq));
      short8 kf1 = *reinterpret_cast<const short8*>(kl + (32 + lq) * 128 + ((c * 32 + hi * 16) ^ swz_lq));
      s0 = MFMA32(kf0, qf[c], s0);
      s1 = MFMA32(kf1, qf[c], s1);
    }
    __builtin_amdgcn_s_setprio(0);

    // stage next V into buf^1 (overlaps softmax/PV)
    if (more) stage_v((char*)vt_lds[cur ^ 1], pi, vd0, vna, vnb);

    // --- fused per-quadrant: exp2 x8 -> pf -> PV MFMAs (keeps <=8 p-floats live) ---
#pragma unroll
    for (int c = 0; c < 4; ++c) {
      float t0_, t1_, t2_, t3_, t4_, t5_, t6_, t7_;
      if (c < 2) {
        const int o = c * 8;
        t0_ = __builtin_exp2f(s0[o + 0]); t1_ = __builtin_exp2f(s0[o + 1]);
        t2_ = __builtin_exp2f(s0[o + 2]); t3_ = __builtin_exp2f(s0[o + 3]);
        t4_ = __builtin_exp2f(s0[o + 4]); t5_ = __builtin_exp2f(s0[o + 5]);
        t6_ = __builtin_exp2f(s0[o + 6]); t7_ = __builtin_exp2f(s0[o + 7]);
      } else {
        const int o = (c - 2) * 8;
        t0_ = __builtin_exp2f(s1[o + 0]); t1_ = __builtin_exp2f(s1[o + 1]);
        t2_ = __builtin_exp2f(s1[o + 2]); t3_ = __builtin_exp2f(s1[o + 3]);
        t4_ = __builtin_exp2f(s1[o + 4]); t5_ = __builtin_exp2f(s1[o + 5]);
        t6_ = __builtin_exp2f(s1[o + 6]); t7_ = __builtin_exp2f(s1[o + 7]);
      }
      ls0 += t0_ + t4_; ls1 += t1_ + t5_; ls2 += t2_ + t6_; ls3 += t3_ + t7_;
      unsigned a0 = cvt_pk_bf16(t0_, t1_), a1 = cvt_pk_bf16(t4_, t5_);
      unsigned b0 = cvt_pk_bf16(t2_, t3_), b1 = cvt_pk_bf16(t6_, t7_);
      pl32_swap(a0, a1); pl32_swap(b0, b1);
      short8 pfc = mk8(a0, b0, a1, b1);
      short8 vf0 = *reinterpret_cast<const short8*>(vl + lq * 128 + ((c * 32 + hi * 16) ^ swz_lq));
      short8 vf1 = *reinterpret_cast<const short8*>(vl + (32 + lq) * 128 + ((c * 32 + hi * 16) ^ swz_lq));
      __builtin_amdgcn_s_setprio(1);
      ot0 = MFMA32(vf0, pfc, ot0);
      ot1 = MFMA32(vf1, pfc, ot1);
      __builtin_amdgcn_s_setprio(0);
    }
    cur ^= 1;
  }

  // ---- epilogue: store fp16 O^T partial [64 d][128 q] + fp32 l partial ----
  const int g = bh * 16 + qblk;
  _Float16* pop = (kv == 0 ? poA : poB) + (size_t)g * 8192;
#pragma unroll
  for (int r = 0; r < 16; ++r) {
    int d = (r & 3) + 8 * (r >> 2) + 4 * hi;
    pop[d * 128 + w * 32 + lq] = (_Float16)ot0[r];
    pop[(32 + d) * 128 + w * 32 + lq] = (_Float16)ot1[r];
  }
  float lsum = (ls0 + ls1) + (ls2 + ls3);
  lsum += __shfl_xor(lsum, 32, 64);
  if (hi == 0) pl[(size_t)(g * S + kv) * 128 + w * 32 + lq] = lsum;
}

// ---------------- merge: O = (P0 + P1) / (l0 + l1), transpose to row-major bf16 ----------------
template <int S>
__global__ __launch_bounds__(256) void merge_kernel(const _Float16* __restrict__ poA,
                                                    const _Float16* __restrict__ poB,
                                                    const float* __restrict__ pl,
                                                    unsigned short* __restrict__ aout) {
  __shared__ unsigned short lo[128][72];
  const int g = blockIdx.x;                 // 512 = (bh, qblk)
  const int bh = g >> 4, qblk = g & 15;
  const int b = bh >> 4, h = bh & 15;
  const int tid = threadIdx.x;
  const int qi = (tid & 31) * 4;
  const int dg = tid >> 5;
  const _Float16* P0 = poA + (size_t)g * 8192;
  const _Float16* P1 = poB + (size_t)g * 8192;
  const float* L = pl + (size_t)g * S * 128;

  float inv[4];
#pragma unroll
  for (int j = 0; j < 4; ++j) {
    float lv = L[qi + j];
    if (S == 2) lv += L[128 + qi + j];
    inv[j] = 1.0f / lv;
  }
#pragma unroll
  for (int dd = 0; dd < 8; ++dd) {
    int d = dg * 8 + dd;
    h4 a = *reinterpret_cast<const h4*>(P0 + d * 128 + qi);
    float o[4];
#pragma unroll
    for (int j = 0; j < 4; ++j) o[j] = (float)a[j];
    if (S == 2) {
      h4 bb = *reinterpret_cast<const h4*>(P1 + d * 128 + qi);
#pragma unroll
      for (int j = 0; j < 4; ++j) o[j] += (float)bb[j];
    }
#pragma unroll
    for (int j = 0; j < 4; ++j) lo[qi + j][d] = f2bf(o[j] * inv[j]);
  }
  __syncthreads();
  const int q = tid >> 1, c0 = (tid & 1) * 32;
  unsigned short* orow = aout + (size_t)(b * 2048 + qblk * 128 + q) * 1024 + h * 64 + c0;
#pragma unroll
  for (int k = 0; k < 4; ++k)
    *reinterpret_cast<short8*>(orow + k * 8) =
        *reinterpret_cast<const short8*>(&lo[q][c0 + k * 8]);
}

// ---------------- host ----------------
extern "C" void kernel_launch(void* const* d_in, const int* in_sizes, int n_in,
                              void* d_out, int out_size, void* d_ws, size_t ws_size,
                              hipStream_t stream) {
  const float* x  = (const float*)d_in[0];
  const float* wq = (const float*)d_in[1];
  const float* bq = (const float*)d_in[2];
  const float* wk = (const float*)d_in[3];
  const float* bk = (const float*)d_in[4];
  const float* wv = (const float*)d_in[5];
  const float* bv = (const float*)d_in[6];
  const float* wo = (const float*)d_in[7];
  const float* bo = (const float*)d_in[8];
  float* out = (float*)d_out;

  char* ws = (char*)d_ws;
  // [0,8M): xb (GEMM phase) / poA (attn+merge)  [8M,16M): wt  [16M,+12K): bias3
  // [16M+64K,+24M): qkvb (attn) -> aob reuse    [42.01M,+8M): poB   pl @ 50.40M
  unsigned short* xb    = (unsigned short*)(ws);
  _Float16*       poA   = (_Float16*)(ws);
  unsigned short* wt    = (unsigned short*)(ws + 8388608);
  float*          bias3 = (float*)(ws + 16777216);
  unsigned short* qkvb  = (unsigned short*)(ws + 16842752);
  unsigned short* aob   = qkvb;
  _Float16*       poB   = (_Float16*)(ws + 42008576);
  const bool s2 = ws_size >= (size_t)51500000;
  float* pl = (float*)(s2 ? (ws + 50397184) : (ws + 42008576));

  cast_x_kernel<<<4096, 256, 0, stream>>>(x, xb);
  prep_w_kernel<<<4096, 256, 0, stream>>>(wq, wk, wv, wo, wt);
  pack_bias_kernel<<<12, 256, 0, stream>>>(bq, bk, bv, bias3);

  // fused QKV projection (Q pre-scaled by 0.125*log2e): [4096][3072] bf16
  gemm_bt_kernel<unsigned short, true><<<768, 256, 0, stream>>>(xb, wt, bias3, qkvb, 3072);

  // attention partials + merge -> aob [4096][1024] bf16
  if (s2) {
    attn_kernel<2><<<1024, 256, 0, stream>>>(qkvb, poA, poB, pl);
    merge_kernel<2><<<512, 256, 0, stream>>>(poA, poB, pl, aob);
  } else {
    attn_kernel<1><<<512, 256, 0, stream>>>(qkvb, poA, poB, pl);
    merge_kernel<1><<<512, 256, 0, stream>>>(poA, poB, pl, aob);
  }

  // output projection -> fp32 d_out [4096][1024]
  gemm_bt_kernel<float, false><<<256, 256, 0, stream>>>(aob, wt + (size_t)3072 * 1024, bo, out, 1024);
}

// Round 11
// 129.349 us; speedup vs baseline: 1.4111x; 1.0748x over previous
//
#include <hip/hip_runtime.h>
#include <stdint.h>
#include <stddef.h>

// MHA: x[2,2048,1024] -> QKV proj (bf16 MFMA) -> flash attn (H=16, Dh=64) -> out proj.
// R11: R10 structure frozen; attn VALU trims only:
//      (1) raw v_exp_f32 via __builtin_amdgcn_exp2f (no libm wrapper),
//      (2) l-sum via ones-MFMA (R9-verified; removes 16 adds/tile + final shuffle),
//      (3) l-store without cross-lane reduce.

typedef __attribute__((ext_vector_type(8))) short short8;
typedef __attribute__((ext_vector_type(4))) float f32x4;
typedef __attribute__((ext_vector_type(16))) float f32x16;
typedef __attribute__((ext_vector_type(4))) unsigned short u16x4;
typedef _Float16 h4 __attribute__((ext_vector_type(4)));

#define MFMA16(a, b, c) __builtin_amdgcn_mfma_f32_16x16x32_bf16((a), (b), (c), 0, 0, 0)
#define MFMA32(a, b, c) __builtin_amdgcn_mfma_f32_32x32x16_bf16((a), (b), (c), 0, 0, 0)
#define AS1 __attribute__((address_space(1)))
#define AS3 __attribute__((address_space(3)))

__device__ __forceinline__ unsigned short f2bf(float f) {
  union { float f; unsigned u; } v; v.f = f;
  unsigned r = v.u + 0x7fffu + ((v.u >> 16) & 1u);   // RNE
  return (unsigned short)(r >> 16);
}

__device__ __forceinline__ float fexp2(float x) {
#if __has_builtin(__builtin_amdgcn_exp2f)
  return __builtin_amdgcn_exp2f(x);     // raw v_exp_f32
#else
  return __builtin_exp2f(x);
#endif
}

__device__ __forceinline__ unsigned cvt_pk_bf16(float lo, float hi) {
  unsigned r;
  asm("v_cvt_pk_bf16_f32 %0, %1, %2" : "=v"(r) : "v"(lo), "v"(hi));
  return r;
}

__device__ __forceinline__ void pl32_swap(unsigned& a, unsigned& b) {
  asm volatile("v_permlane32_swap_b32 %0, %1" : "+v"(a), "+v"(b));
}

__device__ __forceinline__ short8 mk8(unsigned a, unsigned b, unsigned c, unsigned d) {
  union { unsigned u[4]; short8 s; } v;
  v.u[0] = a; v.u[1] = b; v.u[2] = c; v.u[3] = d;
  return v.s;
}

// ---------------- prep ----------------
__global__ __launch_bounds__(256) void cast_x_kernel(const float* __restrict__ x,
                                                     unsigned short* __restrict__ xb) {
  int i = (blockIdx.x * 256 + threadIdx.x) * 4;
  float4 v = *reinterpret_cast<const float4*>(x + i);
  u16x4 o;
  o.x = f2bf(v.x); o.y = f2bf(v.y); o.z = f2bf(v.z); o.w = f2bf(v.w);
  *reinterpret_cast<u16x4*>(xb + i) = o;
}

__global__ __launch_bounds__(256) void prep_w_kernel(const float* __restrict__ wq,
                                                     const float* __restrict__ wk,
                                                     const float* __restrict__ wv,
                                                     const float* __restrict__ wo,
                                                     unsigned short* __restrict__ wt) {
  __shared__ unsigned short t_lds[32][33];
  int bid = blockIdx.x;
  int wsel = bid >> 10;
  int rem = bid & 1023;
  int kb = (rem >> 5) << 5;
  int nb = (rem & 31) << 5;
  const float* W = (wsel == 0) ? wq : (wsel == 1) ? wk : (wsel == 2) ? wv : wo;
  int t = threadIdx.x;
  int r = t >> 3, c = (t & 7) * 4;
  float4 v = *reinterpret_cast<const float4*>(W + (size_t)(kb + r) * 1024 + nb + c);
  t_lds[r][c + 0] = f2bf(v.x);
  t_lds[r][c + 1] = f2bf(v.y);
  t_lds[r][c + 2] = f2bf(v.z);
  t_lds[r][c + 3] = f2bf(v.w);
  __syncthreads();
  u16x4 o;
  o.x = t_lds[c + 0][r]; o.y = t_lds[c + 1][r];
  o.z = t_lds[c + 2][r]; o.w = t_lds[c + 3][r];
  *reinterpret_cast<u16x4*>(wt + (size_t)(wsel * 1024 + nb + r) * 1024 + kb + c) = o;
}

__global__ __launch_bounds__(256) void pack_bias_kernel(const float* __restrict__ bq,
                                                        const float* __restrict__ bk,
                                                        const float* __restrict__ bv,
                                                        float* __restrict__ bias3) {
  int i = blockIdx.x * 256 + threadIdx.x;
  if (i < 3072) bias3[i] = (i < 1024) ? bq[i] : (i < 2048) ? bk[i - 1024] : bv[i - 2048];
}

// ---------------- GEMM (R4 config): 2-phase dbuf, single barrier per K-step ----------------
template <typename OutT, bool QS>
__global__ __launch_bounds__(256) void gemm_bt_kernel(const unsigned short* __restrict__ A,
                                                      const unsigned short* __restrict__ Bt,
                                                      const float* __restrict__ bias,
                                                      OutT* __restrict__ C, int N) {
  constexpr int K = 1024;
  __shared__ __align__(16) unsigned short a_lds[2][128 * 32];
  __shared__ __align__(16) unsigned short b_lds[2][128 * 32];
  const int nb = N >> 7;
  const int nwg = nb << 5;
  const int cpx = nwg >> 3;
  const int wg = ((int)blockIdx.x & 7) * cpx + ((int)blockIdx.x >> 3);  // XCD swizzle
  const int bm = wg / nb;
  const int bn = wg % nb;
  const int m0 = bm << 7, n0 = bn << 7;
  const int tid = threadIdx.x;
  const int w = tid >> 6, l = tid & 63;
  const int lr = l & 15, lg = l >> 4;
  const int wm = (w >> 1) << 6, wn = (w & 1) << 6;

  const int q0 = w * 2, q1 = w * 2 + 1;
  const unsigned short* pa0 = A + (size_t)(m0 + q0 * 16 + (l >> 2)) * K + (l & 3) * 8;
  const unsigned short* pa1 = A + (size_t)(m0 + q1 * 16 + (l >> 2)) * K + (l & 3) * 8;
  const unsigned short* pb0 = Bt + (size_t)(n0 + q0 * 16 + (l >> 2)) * K + (l & 3) * 8;
  const unsigned short* pb1 = Bt + (size_t)(n0 + q1 * 16 + (l >> 2)) * K + (l & 3) * 8;

#define GEMM_STAGE(buf, k0)                                                        \
  do {                                                                             \
    __builtin_amdgcn_global_load_lds((const AS1 void*)(pa0 + (k0)),                \
        (AS3 void*)(&a_lds[buf][q0 * 512]), 16, 0, 0);                             \
    __builtin_amdgcn_global_load_lds((const AS1 void*)(pa1 + (k0)),                \
        (AS3 void*)(&a_lds[buf][q1 * 512]), 16, 0, 0);                             \
    __builtin_amdgcn_global_load_lds((const AS1 void*)(pb0 + (k0)),                \
        (AS3 void*)(&b_lds[buf][q0 * 512]), 16, 0, 0);                             \
    __builtin_amdgcn_global_load_lds((const AS1 void*)(pb1 + (k0)),                \
        (AS3 void*)(&b_lds[buf][q1 * 512]), 16, 0, 0);                             \
  } while (0)

  f32x4 acc[4][4] = {};
  GEMM_STAGE(0, 0);
  __syncthreads();

  int cur = 0;
  for (int k0 = 0; k0 < K; k0 += 32) {
    if (k0 + 32 < K) GEMM_STAGE(cur ^ 1, k0 + 32);
    short8 af[4], bfr[4];
#pragma unroll
    for (int i = 0; i < 4; ++i)
      af[i] = *reinterpret_cast<const short8*>(&a_lds[cur][(wm + i * 16 + lr) * 32 + lg * 8]);
#pragma unroll
    for (int i = 0; i < 4; ++i)
      bfr[i] = *reinterpret_cast<const short8*>(&b_lds[cur][(wn + i * 16 + lr) * 32 + lg * 8]);
#pragma unroll
    for (int i = 0; i < 4; ++i)
#pragma unroll
      for (int j = 0; j < 4; ++j)
        acc[i][j] = MFMA16(af[i], bfr[j], acc[i][j]);
    __syncthreads();
    cur ^= 1;
  }
#undef GEMM_STAGE

  const float scale = (QS && n0 < 1024) ? 0.18033688011111f : 1.0f;  // 0.125*log2e
#pragma unroll
  for (int i = 0; i < 4; ++i) {
#pragma unroll
    for (int j = 0; j < 4; ++j) {
#pragma unroll
      for (int r = 0; r < 4; ++r) {
        int m = m0 + wm + i * 16 + lg * 4 + r;
        int n = n0 + wn + j * 16 + lr;
        float val = (acc[i][j][r] + bias[n]) * scale;
        if constexpr (sizeof(OutT) == 2) {
          C[(size_t)m * N + n] = (OutT)f2bf(val);
        } else {
          C[(size_t)m * N + n] = val;
        }
      }
    }
  }
}

// ---------------- flash attention ----------------
__device__ __forceinline__ void stage_v(char* vw, int pi, int vd0, short8 va, short8 vb) {
  union { short8 s; unsigned u[4]; } ua, ub;
  ua.s = va; ub.s = vb;
#pragma unroll
  for (int jr = 0; jr < 4; ++jr) {
    unsigned w0 = __builtin_amdgcn_perm(ub.u[jr], ua.u[jr], 0x05040100u);  // lo halves
    unsigned w1 = __builtin_amdgcn_perm(ub.u[jr], ua.u[jr], 0x07060302u);  // hi halves
    int d0 = vd0 + 2 * jr, d1 = d0 + 1;
    *reinterpret_cast<unsigned*>(vw + d0 * 128 + ((4 * pi) ^ ((d0 & 7) << 4))) = w0;
    *reinterpret_cast<unsigned*>(vw + d1 * 128 + ((4 * pi) ^ ((d1 & 7) << 4))) = w1;
  }
}

// grid 512*S: (b,h)[32] x qblk[16] x kv[S]; 4 waves x 32 q rows; block covers
// t in [kv*2048/S, +2048/S) in 64-t tiles. Fixed-base softmax (p = exp2(s), Q pre-scaled
// into log2 domain); l via ones-MFMA (every C row = sum_t P[t][q]); fp16 O^T partials
// + fp32 l partials to ws; merge kernel normalizes.
template <int S>
__global__ __launch_bounds__(256, 4) void attn_kernel(const unsigned short* __restrict__ qkv,
                                                      _Float16* __restrict__ poA,
                                                      _Float16* __restrict__ poB,
                                                      float* __restrict__ pl) {
  constexpr int TLEN = 2048 / S;
  __shared__ __align__(16) unsigned short k_lds[2][64 * 64];   // [t][d] swizzled, dbuf
  __shared__ __align__(16) unsigned short vt_lds[2][64 * 64];  // [d][t] swizzled, dbuf
  const int tid = threadIdx.x;
  const int w = tid >> 6, l = tid & 63;
  const int lq = l & 31;
  const int hi = l >> 5;
  const int nwg = 512 * S;
  const int wg = ((int)blockIdx.x & 7) * (nwg >> 3) + ((int)blockIdx.x >> 3);  // XCD swizzle
  int bh, qblk, kv;
  if (S == 2) { bh = wg >> 5; qblk = (wg >> 1) & 15; kv = wg & 1; }
  else        { bh = wg >> 4; qblk = wg & 15;        kv = 0; }
  const int b = bh >> 4, h = bh & 15;
  const size_t rowbase = (size_t)b * 2048;
  const int q0 = qblk * 128 + w * 32;

  // Q fragments (B-operand); Q pre-scaled by 0.125*log2e in GEMM epilogue.
  short8 qf[4];
  {
    const unsigned short* qrow = qkv + (rowbase + q0 + lq) * 3072 + h * 64 + hi * 8;
#pragma unroll
    for (int c = 0; c < 4; ++c)
      qf[c] = *reinterpret_cast<const short8*>(qrow + c * 16);
  }

  // K staging via global_load_lds, pre-swizzled source (R7-verified formula).
  const int colsw = (16 * (l & 7)) ^ ((l >> 3) << 4);
  const char* ksrc = (const char*)(qkv + (rowbase + kv * TLEN) * 3072 + 1024 + h * 64) +
                     (size_t)(16 * w + (l >> 3)) * 6144 + colsw;
  const int kdst = w * 2048;                  // wave-uniform byte offset in 8 KB plane

  // V staging (reg + perm): lane covers t = {2pi, 2pi+1}, d = vd0..vd0+7.
  const int pi = tid & 31;
  const int vd0 = (tid >> 5) * 8;
  const unsigned short* vbase = qkv + (rowbase + kv * TLEN) * 3072 + 2048 + h * 64;
  const int swz_lq = (lq & 7) << 4;

  short8 ones;                          // bf16 1.0 x8 (A-operand for l-sum MFMA)
  {
    union { unsigned u[4]; short8 s; } o_;
    o_.u[0] = o_.u[1] = o_.u[2] = o_.u[3] = 0x3F803F80u;
    ones = o_.s;
  }

  f32x16 ot0 = {}, ot1 = {}, lacc = {};

  // prologue: stage tile 0 into buf 0
  __builtin_amdgcn_global_load_lds((const AS1 void*)ksrc,
                                   (AS3 void*)((char*)k_lds[0] + kdst), 16, 0, 0);
  __builtin_amdgcn_global_load_lds((const AS1 void*)(ksrc + 49152),
                                   (AS3 void*)((char*)k_lds[0] + kdst + 1024), 16, 0, 0);
  ksrc += 393216;
  {
    short8 va = *reinterpret_cast<const short8*>(vbase + (size_t)(2 * pi) * 3072 + vd0);
    short8 vb = *reinterpret_cast<const short8*>(vbase + (size_t)(2 * pi + 1) * 3072 + vd0);
    stage_v((char*)vt_lds[0], pi, vd0, va, vb);
  }

  int cur = 0;
  for (int t0 = 0; t0 < TLEN; t0 += 64) {
    __syncthreads();   // drains K gll + V ds_writes into buf[cur]; prev readers done
    const bool more = (t0 + 64) < TLEN;
    short8 vna, vnb;
    if (more) {
      char* kd = (char*)k_lds[cur ^ 1] + kdst;
      __builtin_amdgcn_global_load_lds((const AS1 void*)ksrc, (AS3 void*)kd, 16, 0, 0);
      __builtin_amdgcn_global_load_lds((const AS1 void*)(ksrc + 49152),
                                       (AS3 void*)(kd + 1024), 16, 0, 0);
      ksrc += 393216;
      vna = *reinterpret_cast<const short8*>(vbase + (size_t)(t0 + 64 + 2 * pi) * 3072 + vd0);
      vnb = *reinterpret_cast<const short8*>(vbase + (size_t)(t0 + 65 + 2 * pi) * 3072 + vd0);
    }
    const char* kl = (const char*)k_lds[cur];
    const char* vl = (const char*)vt_lds[cur];

    // --- QK^T (swapped): lane owns S^T[.][q=lq] ---
    f32x16 s0 = {}, s1 = {};
    __builtin_amdgcn_s_setprio(1);
#pragma unroll
    for (int c = 0; c < 4; ++c) {
      short8 kf0 = *reinterpret_cast<const short8*>(kl + lq * 128 + ((c * 32 + hi * 16) ^ swz_lq));
      short8 kf1 = *reinterpret_cast<const short8*>(kl + (32 + lq) * 128 + ((c * 32 + hi * 16) ^ swz_lq));
      s0 = MFMA32(kf0, qf[c], s0);
      s1 = MFMA32(kf1, qf[c], s1);
    }
    __builtin_amdgcn_s_setprio(0);

    // stage next V into buf^1 (overlaps softmax/PV)
    if (more) stage_v((char*)vt_lds[cur ^ 1], pi, vd0, vna, vnb);

    // --- fused per-quadrant: exp2 x8 -> pf -> {l-MFMA, PV MFMAs} ---
#pragma unroll
    for (int c = 0; c < 4; ++c) {
      float t0_, t1_, t2_, t3_, t4_, t5_, t6_, t7_;
      if (c < 2) {
        const int o = c * 8;
        t0_ = fexp2(s0[o + 0]); t1_ = fexp2(s0[o + 1]);
        t2_ = fexp2(s0[o + 2]); t3_ = fexp2(s0[o + 3]);
        t4_ = fexp2(s0[o + 4]); t5_ = fexp2(s0[o + 5]);
        t6_ = fexp2(s0[o + 6]); t7_ = fexp2(s0[o + 7]);
      } else {
        const int o = (c - 2) * 8;
        t0_ = fexp2(s1[o + 0]); t1_ = fexp2(s1[o + 1]);
        t2_ = fexp2(s1[o + 2]); t3_ = fexp2(s1[o + 3]);
        t4_ = fexp2(s1[o + 4]); t5_ = fexp2(s1[o + 5]);
        t6_ = fexp2(s1[o + 6]); t7_ = fexp2(s1[o + 7]);
      }
      unsigned a0 = cvt_pk_bf16(t0_, t1_), a1 = cvt_pk_bf16(t4_, t5_);
      unsigned b0 = cvt_pk_bf16(t2_, t3_), b1 = cvt_pk_bf16(t6_, t7_);
      pl32_swap(a0, a1); pl32_swap(b0, b1);
      short8 pfc = mk8(a0, b0, a1, b1);
      short8 vf0 = *reinterpret_cast<const short8*>(vl + lq * 128 + ((c * 32 + hi * 16) ^ swz_lq));
      short8 vf1 = *reinterpret_cast<const short8*>(vl + (32 + lq) * 128 + ((c * 32 + hi * 16) ^ swz_lq));
      __builtin_amdgcn_s_setprio(1);
      ot0 = MFMA32(vf0, pfc, ot0);
      ot1 = MFMA32(vf1, pfc, ot1);
      lacc = MFMA32(ones, pfc, lacc);
      __builtin_amdgcn_s_setprio(0);
    }
    cur ^= 1;
  }

  // ---- epilogue: store fp16 O^T partial [64 d][128 q] + fp32 l partial ----
  const int g = bh * 16 + qblk;
  _Float16* pop = (kv == 0 ? poA : poB) + (size_t)g * 8192;
#pragma unroll
  for (int r = 0; r < 16; ++r) {
    int d = (r & 3) + 8 * (r >> 2) + 4 * hi;
    pop[d * 128 + w * 32 + lq] = (_Float16)ot0[r];
    pop[(32 + d) * 128 + w * 32 + lq] = (_Float16)ot1[r];
  }
  // lacc rows all equal Σ_t P[t][q]; lane holds col q = lane&31 -> no cross-lane reduce.
  if (hi == 0) pl[(size_t)(g * S + kv) * 128 + w * 32 + lq] = lacc[0];
}

// ---------------- merge: O = (P0 + P1) / (l0 + l1), transpose to row-major bf16 ----------------
template <int S>
__global__ __launch_bounds__(256) void merge_kernel(const _Float16* __restrict__ poA,
                                                    const _Float16* __restrict__ poB,
                                                    const float* __restrict__ pl,
                                                    unsigned short* __restrict__ aout) {
  __shared__ unsigned short lo[128][72];
  const int g = blockIdx.x;                 // 512 = (bh, qblk)
  const int bh = g >> 4, qblk = g & 15;
  const int b = bh >> 4, h = bh & 15;
  const int tid = threadIdx.x;
  const int qi = (tid & 31) * 4;
  const int dg = tid >> 5;
  const _Float16* P0 = poA + (size_t)g * 8192;
  const _Float16* P1 = poB + (size_t)g * 8192;
  const float* L = pl + (size_t)g * S * 128;

  float inv[4];
#pragma unroll
  for (int j = 0; j < 4; ++j) {
    float lv = L[qi + j];
    if (S == 2) lv += L[128 + qi + j];
    inv[j] = 1.0f / lv;
  }
#pragma unroll
  for (int dd = 0; dd < 8; ++dd) {
    int d = dg * 8 + dd;
    h4 a = *reinterpret_cast<const h4*>(P0 + d * 128 + qi);
    float o[4];
#pragma unroll
    for (int j = 0; j < 4; ++j) o[j] = (float)a[j];
    if (S == 2) {
      h4 bb = *reinterpret_cast<const h4*>(P1 + d * 128 + qi);
#pragma unroll
      for (int j = 0; j < 4; ++j) o[j] += (float)bb[j];
    }
#pragma unroll
    for (int j = 0; j < 4; ++j) lo[qi + j][d] = f2bf(o[j] * inv[j]);
  }
  __syncthreads();
  const int q = tid >> 1, c0 = (tid & 1) * 32;
  unsigned short* orow = aout + (size_t)(b * 2048 + qblk * 128 + q) * 1024 + h * 64 + c0;
#pragma unroll
  for (int k = 0; k < 4; ++k)
    *reinterpret_cast<short8*>(orow + k * 8) =
        *reinterpret_cast<const short8*>(&lo[q][c0 + k * 8]);
}

// ---------------- host ----------------
extern "C" void kernel_launch(void* const* d_in, const int* in_sizes, int n_in,
                              void* d_out, int out_size, void* d_ws, size_t ws_size,
                              hipStream_t stream) {
  const float* x  = (const float*)d_in[0];
  const float* wq = (const float*)d_in[1];
  const float* bq = (const float*)d_in[2];
  const float* wk = (const float*)d_in[3];
  const float* bk = (const float*)d_in[4];
  const float* wv = (const float*)d_in[5];
  const float* bv = (const float*)d_in[6];
  const float* wo = (const float*)d_in[7];
  const float* bo = (const float*)d_in[8];
  float* out = (float*)d_out;

  char* ws = (char*)d_ws;
  // [0,8M): xb (GEMM phase) / poA (attn+merge)  [8M,16M): wt  [16M,+12K): bias3
  // [16M+64K,+24M): qkvb (attn) -> aob reuse    [42.01M,+8M): poB   pl @ 50.40M
  unsigned short* xb    = (unsigned short*)(ws);
  _Float16*       poA   = (_Float16*)(ws);
  unsigned short* wt    = (unsigned short*)(ws + 8388608);
  float*          bias3 = (float*)(ws + 16777216);
  unsigned short* qkvb  = (unsigned short*)(ws + 16842752);
  unsigned short* aob   = qkvb;
  _Float16*       poB   = (_Float16*)(ws + 42008576);
  const bool s2 = ws_size >= (size_t)51500000;
  float* pl = (float*)(s2 ? (ws + 50397184) : (ws + 42008576));

  cast_x_kernel<<<4096, 256, 0, stream>>>(x, xb);
  prep_w_kernel<<<4096, 256, 0, stream>>>(wq, wk, wv, wo, wt);
  pack_bias_kernel<<<12, 256, 0, stream>>>(bq, bk, bv, bias3);

  // fused QKV projection (Q pre-scaled by 0.125*log2e): [4096][3072] bf16
  gemm_bt_kernel<unsigned short, true><<<768, 256, 0, stream>>>(xb, wt, bias3, qkvb, 3072);

  // attention partials + merge -> aob [4096][1024] bf16
  if (s2) {
    attn_kernel<2><<<1024, 256, 0, stream>>>(qkvb, poA, poB, pl);
    merge_kernel<2><<<512, 256, 0, stream>>>(poA, poB, pl, aob);
  } else {
    attn_kernel<1><<<512, 256, 0, stream>>>(qkvb, poA, poB, pl);
    merge_kernel<1><<<512, 256, 0, stream>>>(poA, poB, pl, aob);
  }

  // output projection -> fp32 d_out [4096][1024]
  gemm_bt_kernel<float, false><<<256, 256, 0, stream>>>(aob, wt + (size_t)3072 * 1024, bo, out, 1024);
}

// Round 12
// 124.958 us; speedup vs baseline: 1.4607x; 1.0351x over previous
//
#include <hip/hip_runtime.h>
#include <stdint.h>
#include <stddef.h>

// MHA: x[2,2048,1024] -> QKV proj (bf16 MFMA) -> flash attn (H=16, Dh=64) -> out proj.
// R12: R11 frozen; prep stage fused into ONE dispatch (cast_x + prep_w + pack_bias,
//      block-uniform branch) to cut launch overhead and overlap the three BW-bound passes.

typedef __attribute__((ext_vector_type(8))) short short8;
typedef __attribute__((ext_vector_type(4))) float f32x4;
typedef __attribute__((ext_vector_type(16))) float f32x16;
typedef __attribute__((ext_vector_type(4))) unsigned short u16x4;
typedef _Float16 h4 __attribute__((ext_vector_type(4)));

#define MFMA16(a, b, c) __builtin_amdgcn_mfma_f32_16x16x32_bf16((a), (b), (c), 0, 0, 0)
#define MFMA32(a, b, c) __builtin_amdgcn_mfma_f32_32x32x16_bf16((a), (b), (c), 0, 0, 0)
#define AS1 __attribute__((address_space(1)))
#define AS3 __attribute__((address_space(3)))

__device__ __forceinline__ unsigned short f2bf(float f) {
  union { float f; unsigned u; } v; v.f = f;
  unsigned r = v.u + 0x7fffu + ((v.u >> 16) & 1u);   // RNE
  return (unsigned short)(r >> 16);
}

__device__ __forceinline__ float fexp2(float x) {
#if __has_builtin(__builtin_amdgcn_exp2f)
  return __builtin_amdgcn_exp2f(x);     // raw v_exp_f32
#else
  return __builtin_exp2f(x);
#endif
}

__device__ __forceinline__ unsigned cvt_pk_bf16(float lo, float hi) {
  unsigned r;
  asm("v_cvt_pk_bf16_f32 %0, %1, %2" : "=v"(r) : "v"(lo), "v"(hi));
  return r;
}

__device__ __forceinline__ void pl32_swap(unsigned& a, unsigned& b) {
  asm volatile("v_permlane32_swap_b32 %0, %1" : "+v"(a), "+v"(b));
}

__device__ __forceinline__ short8 mk8(unsigned a, unsigned b, unsigned c, unsigned d) {
  union { unsigned u[4]; short8 s; } v;
  v.u[0] = a; v.u[1] = b; v.u[2] = c; v.u[3] = d;
  return v.s;
}

// ---------------- fused prep: [0,4096) prep_w | [4096,8192) cast_x | 8192 pack_bias ----
__global__ __launch_bounds__(256) void prep_all_kernel(const float* __restrict__ x,
                                                       const float* __restrict__ wq,
                                                       const float* __restrict__ wk,
                                                       const float* __restrict__ wv,
                                                       const float* __restrict__ wo,
                                                       const float* __restrict__ bq,
                                                       const float* __restrict__ bk,
                                                       const float* __restrict__ bv,
                                                       unsigned short* __restrict__ xb,
                                                       unsigned short* __restrict__ wt,
                                                       float* __restrict__ bias3) {
  __shared__ unsigned short t_lds[32][33];
  const int bid = blockIdx.x;
  if (bid < 4096) {
    // transpose+cast one 32x32 tile of one weight into wt[4096][1024]
    int wsel = bid >> 10;
    int rem = bid & 1023;
    int kb = (rem >> 5) << 5;
    int nb = (rem & 31) << 5;
    const float* W = (wsel == 0) ? wq : (wsel == 1) ? wk : (wsel == 2) ? wv : wo;
    int t = threadIdx.x;
    int r = t >> 3, c = (t & 7) * 4;
    float4 v = *reinterpret_cast<const float4*>(W + (size_t)(kb + r) * 1024 + nb + c);
    t_lds[r][c + 0] = f2bf(v.x);
    t_lds[r][c + 1] = f2bf(v.y);
    t_lds[r][c + 2] = f2bf(v.z);
    t_lds[r][c + 3] = f2bf(v.w);
    __syncthreads();
    u16x4 o;
    o.x = t_lds[c + 0][r]; o.y = t_lds[c + 1][r];
    o.z = t_lds[c + 2][r]; o.w = t_lds[c + 3][r];
    *reinterpret_cast<u16x4*>(wt + (size_t)(wsel * 1024 + nb + r) * 1024 + kb + c) = o;
  } else if (bid < 8192) {
    int i = ((bid - 4096) * 256 + threadIdx.x) * 4;
    float4 v = *reinterpret_cast<const float4*>(x + i);
    u16x4 o;
    o.x = f2bf(v.x); o.y = f2bf(v.y); o.z = f2bf(v.z); o.w = f2bf(v.w);
    *reinterpret_cast<u16x4*>(xb + i) = o;
  } else {
#pragma unroll
    for (int k = 0; k < 12; ++k) {
      int i = k * 256 + threadIdx.x;
      bias3[i] = (i < 1024) ? bq[i] : (i < 2048) ? bk[i - 1024] : bv[i - 2048];
    }
  }
}

// ---------------- GEMM (R4 config): 2-phase dbuf, single barrier per K-step ----------------
template <typename OutT, bool QS>
__global__ __launch_bounds__(256) void gemm_bt_kernel(const unsigned short* __restrict__ A,
                                                      const unsigned short* __restrict__ Bt,
                                                      const float* __restrict__ bias,
                                                      OutT* __restrict__ C, int N) {
  constexpr int K = 1024;
  __shared__ __align__(16) unsigned short a_lds[2][128 * 32];
  __shared__ __align__(16) unsigned short b_lds[2][128 * 32];
  const int nb = N >> 7;
  const int nwg = nb << 5;
  const int cpx = nwg >> 3;
  const int wg = ((int)blockIdx.x & 7) * cpx + ((int)blockIdx.x >> 3);  // XCD swizzle
  const int bm = wg / nb;
  const int bn = wg % nb;
  const int m0 = bm << 7, n0 = bn << 7;
  const int tid = threadIdx.x;
  const int w = tid >> 6, l = tid & 63;
  const int lr = l & 15, lg = l >> 4;
  const int wm = (w >> 1) << 6, wn = (w & 1) << 6;

  const int q0 = w * 2, q1 = w * 2 + 1;
  const unsigned short* pa0 = A + (size_t)(m0 + q0 * 16 + (l >> 2)) * K + (l & 3) * 8;
  const unsigned short* pa1 = A + (size_t)(m0 + q1 * 16 + (l >> 2)) * K + (l & 3) * 8;
  const unsigned short* pb0 = Bt + (size_t)(n0 + q0 * 16 + (l >> 2)) * K + (l & 3) * 8;
  const unsigned short* pb1 = Bt + (size_t)(n0 + q1 * 16 + (l >> 2)) * K + (l & 3) * 8;

#define GEMM_STAGE(buf, k0)                                                        \
  do {                                                                             \
    __builtin_amdgcn_global_load_lds((const AS1 void*)(pa0 + (k0)),                \
        (AS3 void*)(&a_lds[buf][q0 * 512]), 16, 0, 0);                             \
    __builtin_amdgcn_global_load_lds((const AS1 void*)(pa1 + (k0)),                \
        (AS3 void*)(&a_lds[buf][q1 * 512]), 16, 0, 0);                             \
    __builtin_amdgcn_global_load_lds((const AS1 void*)(pb0 + (k0)),                \
        (AS3 void*)(&b_lds[buf][q0 * 512]), 16, 0, 0);                             \
    __builtin_amdgcn_global_load_lds((const AS1 void*)(pb1 + (k0)),                \
        (AS3 void*)(&b_lds[buf][q1 * 512]), 16, 0, 0);                             \
  } while (0)

  f32x4 acc[4][4] = {};
  GEMM_STAGE(0, 0);
  __syncthreads();

  int cur = 0;
  for (int k0 = 0; k0 < K; k0 += 32) {
    if (k0 + 32 < K) GEMM_STAGE(cur ^ 1, k0 + 32);
    short8 af[4], bfr[4];
#pragma unroll
    for (int i = 0; i < 4; ++i)
      af[i] = *reinterpret_cast<const short8*>(&a_lds[cur][(wm + i * 16 + lr) * 32 + lg * 8]);
#pragma unroll
    for (int i = 0; i < 4; ++i)
      bfr[i] = *reinterpret_cast<const short8*>(&b_lds[cur][(wn + i * 16 + lr) * 32 + lg * 8]);
#pragma unroll
    for (int i = 0; i < 4; ++i)
#pragma unroll
      for (int j = 0; j < 4; ++j)
        acc[i][j] = MFMA16(af[i], bfr[j], acc[i][j]);
    __syncthreads();
    cur ^= 1;
  }
#undef GEMM_STAGE

  const float scale = (QS && n0 < 1024) ? 0.18033688011111f : 1.0f;  // 0.125*log2e
#pragma unroll
  for (int i = 0; i < 4; ++i) {
#pragma unroll
    for (int j = 0; j < 4; ++j) {
#pragma unroll
      for (int r = 0; r < 4; ++r) {
        int m = m0 + wm + i * 16 + lg * 4 + r;
        int n = n0 + wn + j * 16 + lr;
        float val = (acc[i][j][r] + bias[n]) * scale;
        if constexpr (sizeof(OutT) == 2) {
          C[(size_t)m * N + n] = (OutT)f2bf(val);
        } else {
          C[(size_t)m * N + n] = val;
        }
      }
    }
  }
}

// ---------------- flash attention ----------------
__device__ __forceinline__ void stage_v(char* vw, int pi, int vd0, short8 va, short8 vb) {
  union { short8 s; unsigned u[4]; } ua, ub;
  ua.s = va; ub.s = vb;
#pragma unroll
  for (int jr = 0; jr < 4; ++jr) {
    unsigned w0 = __builtin_amdgcn_perm(ub.u[jr], ua.u[jr], 0x05040100u);  // lo halves
    unsigned w1 = __builtin_amdgcn_perm(ub.u[jr], ua.u[jr], 0x07060302u);  // hi halves
    int d0 = vd0 + 2 * jr, d1 = d0 + 1;
    *reinterpret_cast<unsigned*>(vw + d0 * 128 + ((4 * pi) ^ ((d0 & 7) << 4))) = w0;
    *reinterpret_cast<unsigned*>(vw + d1 * 128 + ((4 * pi) ^ ((d1 & 7) << 4))) = w1;
  }
}

// grid 512*S: (b,h)[32] x qblk[16] x kv[S]; 4 waves x 32 q rows; block covers
// t in [kv*2048/S, +2048/S) in 64-t tiles. Fixed-base softmax (p = exp2(s), Q pre-scaled
// into log2 domain); l via ones-MFMA; fp16 O^T partials + fp32 l partials; merge normalizes.
template <int S>
__global__ __launch_bounds__(256, 4) void attn_kernel(const unsigned short* __restrict__ qkv,
                                                      _Float16* __restrict__ poA,
                                                      _Float16* __restrict__ poB,
                                                      float* __restrict__ pl) {
  constexpr int TLEN = 2048 / S;
  __shared__ __align__(16) unsigned short k_lds[2][64 * 64];   // [t][d] swizzled, dbuf
  __shared__ __align__(16) unsigned short vt_lds[2][64 * 64];  // [d][t] swizzled, dbuf
  const int tid = threadIdx.x;
  const int w = tid >> 6, l = tid & 63;
  const int lq = l & 31;
  const int hi = l >> 5;
  const int nwg = 512 * S;
  const int wg = ((int)blockIdx.x & 7) * (nwg >> 3) + ((int)blockIdx.x >> 3);  // XCD swizzle
  int bh, qblk, kv;
  if (S == 2) { bh = wg >> 5; qblk = (wg >> 1) & 15; kv = wg & 1; }
  else        { bh = wg >> 4; qblk = wg & 15;        kv = 0; }
  const int b = bh >> 4, h = bh & 15;
  const size_t rowbase = (size_t)b * 2048;
  const int q0 = qblk * 128 + w * 32;

  // Q fragments (B-operand); Q pre-scaled by 0.125*log2e in GEMM epilogue.
  short8 qf[4];
  {
    const unsigned short* qrow = qkv + (rowbase + q0 + lq) * 3072 + h * 64 + hi * 8;
#pragma unroll
    for (int c = 0; c < 4; ++c)
      qf[c] = *reinterpret_cast<const short8*>(qrow + c * 16);
  }

  // K staging via global_load_lds, pre-swizzled source (R7-verified formula).
  const int colsw = (16 * (l & 7)) ^ ((l >> 3) << 4);
  const char* ksrc = (const char*)(qkv + (rowbase + kv * TLEN) * 3072 + 1024 + h * 64) +
                     (size_t)(16 * w + (l >> 3)) * 6144 + colsw;
  const int kdst = w * 2048;                  // wave-uniform byte offset in 8 KB plane

  // V staging (reg + perm): lane covers t = {2pi, 2pi+1}, d = vd0..vd0+7.
  const int pi = tid & 31;
  const int vd0 = (tid >> 5) * 8;
  const unsigned short* vbase = qkv + (rowbase + kv * TLEN) * 3072 + 2048 + h * 64;
  const int swz_lq = (lq & 7) << 4;

  short8 ones;                          // bf16 1.0 x8 (A-operand for l-sum MFMA)
  {
    union { unsigned u[4]; short8 s; } o_;
    o_.u[0] = o_.u[1] = o_.u[2] = o_.u[3] = 0x3F803F80u;
    ones = o_.s;
  }

  f32x16 ot0 = {}, ot1 = {}, lacc = {};

  // prologue: stage tile 0 into buf 0
  __builtin_amdgcn_global_load_lds((const AS1 void*)ksrc,
                                   (AS3 void*)((char*)k_lds[0] + kdst), 16, 0, 0);
  __builtin_amdgcn_global_load_lds((const AS1 void*)(ksrc + 49152),
                                   (AS3 void*)((char*)k_lds[0] + kdst + 1024), 16, 0, 0);
  ksrc += 393216;
  {
    short8 va = *reinterpret_cast<const short8*>(vbase + (size_t)(2 * pi) * 3072 + vd0);
    short8 vb = *reinterpret_cast<const short8*>(vbase + (size_t)(2 * pi + 1) * 3072 + vd0);
    stage_v((char*)vt_lds[0], pi, vd0, va, vb);
  }

  int cur = 0;
  for (int t0 = 0; t0 < TLEN; t0 += 64) {
    __syncthreads();   // drains K gll + V ds_writes into buf[cur]; prev readers done
    const bool more = (t0 + 64) < TLEN;
    short8 vna, vnb;
    if (more) {
      char* kd = (char*)k_lds[cur ^ 1] + kdst;
      __builtin_amdgcn_global_load_lds((const AS1 void*)ksrc, (AS3 void*)kd, 16, 0, 0);
      __builtin_amdgcn_global_load_lds((const AS1 void*)(ksrc + 49152),
                                       (AS3 void*)(kd + 1024), 16, 0, 0);
      ksrc += 393216;
      vna = *reinterpret_cast<const short8*>(vbase + (size_t)(t0 + 64 + 2 * pi) * 3072 + vd0);
      vnb = *reinterpret_cast<const short8*>(vbase + (size_t)(t0 + 65 + 2 * pi) * 3072 + vd0);
    }
    const char* kl = (const char*)k_lds[cur];
    const char* vl = (const char*)vt_lds[cur];

    // --- QK^T (swapped): lane owns S^T[.][q=lq] ---
    f32x16 s0 = {}, s1 = {};
    __builtin_amdgcn_s_setprio(1);
#pragma unroll
    for (int c = 0; c < 4; ++c) {
      short8 kf0 = *reinterpret_cast<const short8*>(kl + lq * 128 + ((c * 32 + hi * 16) ^ swz_lq));
      short8 kf1 = *reinterpret_cast<const short8*>(kl + (32 + lq) * 128 + ((c * 32 + hi * 16) ^ swz_lq));
      s0 = MFMA32(kf0, qf[c], s0);
      s1 = MFMA32(kf1, qf[c], s1);
    }
    __builtin_amdgcn_s_setprio(0);

    // stage next V into buf^1 (overlaps softmax/PV)
    if (more) stage_v((char*)vt_lds[cur ^ 1], pi, vd0, vna, vnb);

    // --- fused per-quadrant: exp2 x8 -> pf -> {l-MFMA, PV MFMAs} ---
#pragma unroll
    for (int c = 0; c < 4; ++c) {
      float t0_, t1_, t2_, t3_, t4_, t5_, t6_, t7_;
      if (c < 2) {
        const int o = c * 8;
        t0_ = fexp2(s0[o + 0]); t1_ = fexp2(s0[o + 1]);
        t2_ = fexp2(s0[o + 2]); t3_ = fexp2(s0[o + 3]);
        t4_ = fexp2(s0[o + 4]); t5_ = fexp2(s0[o + 5]);
        t6_ = fexp2(s0[o + 6]); t7_ = fexp2(s0[o + 7]);
      } else {
        const int o = (c - 2) * 8;
        t0_ = fexp2(s1[o + 0]); t1_ = fexp2(s1[o + 1]);
        t2_ = fexp2(s1[o + 2]); t3_ = fexp2(s1[o + 3]);
        t4_ = fexp2(s1[o + 4]); t5_ = fexp2(s1[o + 5]);
        t6_ = fexp2(s1[o + 6]); t7_ = fexp2(s1[o + 7]);
      }
      unsigned a0 = cvt_pk_bf16(t0_, t1_), a1 = cvt_pk_bf16(t4_, t5_);
      unsigned b0 = cvt_pk_bf16(t2_, t3_), b1 = cvt_pk_bf16(t6_, t7_);
      pl32_swap(a0, a1); pl32_swap(b0, b1);
      short8 pfc = mk8(a0, b0, a1, b1);
      short8 vf0 = *reinterpret_cast<const short8*>(vl + lq * 128 + ((c * 32 + hi * 16) ^ swz_lq));
      short8 vf1 = *reinterpret_cast<const short8*>(vl + (32 + lq) * 128 + ((c * 32 + hi * 16) ^ swz_lq));
      __builtin_amdgcn_s_setprio(1);
      ot0 = MFMA32(vf0, pfc, ot0);
      ot1 = MFMA32(vf1, pfc, ot1);
      lacc = MFMA32(ones, pfc, lacc);
      __builtin_amdgcn_s_setprio(0);
    }
    cur ^= 1;
  }

  // ---- epilogue: store fp16 O^T partial [64 d][128 q] + fp32 l partial ----
  const int g = bh * 16 + qblk;
  _Float16* pop = (kv == 0 ? poA : poB) + (size_t)g * 8192;
#pragma unroll
  for (int r = 0; r < 16; ++r) {
    int d = (r & 3) + 8 * (r >> 2) + 4 * hi;
    pop[d * 128 + w * 32 + lq] = (_Float16)ot0[r];
    pop[(32 + d) * 128 + w * 32 + lq] = (_Float16)ot1[r];
  }
  // lacc rows all equal Σ_t P[t][q]; lane holds col q = lane&31 -> no cross-lane reduce.
  if (hi == 0) pl[(size_t)(g * S + kv) * 128 + w * 32 + lq] = lacc[0];
}

// ---------------- merge: O = (P0 + P1) / (l0 + l1), transpose to row-major bf16 ----------------
template <int S>
__global__ __launch_bounds__(256) void merge_kernel(const _Float16* __restrict__ poA,
                                                    const _Float16* __restrict__ poB,
                                                    const float* __restrict__ pl,
                                                    unsigned short* __restrict__ aout) {
  __shared__ unsigned short lo[128][72];
  const int g = blockIdx.x;                 // 512 = (bh, qblk)
  const int bh = g >> 4, qblk = g & 15;
  const int b = bh >> 4, h = bh & 15;
  const int tid = threadIdx.x;
  const int qi = (tid & 31) * 4;
  const int dg = tid >> 5;
  const _Float16* P0 = poA + (size_t)g * 8192;
  const _Float16* P1 = poB + (size_t)g * 8192;
  const float* L = pl + (size_t)g * S * 128;

  float inv[4];
#pragma unroll
  for (int j = 0; j < 4; ++j) {
    float lv = L[qi + j];
    if (S == 2) lv += L[128 + qi + j];
    inv[j] = 1.0f / lv;
  }
#pragma unroll
  for (int dd = 0; dd < 8; ++dd) {
    int d = dg * 8 + dd;
    h4 a = *reinterpret_cast<const h4*>(P0 + d * 128 + qi);
    float o[4];
#pragma unroll
    for (int j = 0; j < 4; ++j) o[j] = (float)a[j];
    if (S == 2) {
      h4 bb = *reinterpret_cast<const h4*>(P1 + d * 128 + qi);
#pragma unroll
      for (int j = 0; j < 4; ++j) o[j] += (float)bb[j];
    }
#pragma unroll
    for (int j = 0; j < 4; ++j) lo[qi + j][d] = f2bf(o[j] * inv[j]);
  }
  __syncthreads();
  const int q = tid >> 1, c0 = (tid & 1) * 32;
  unsigned short* orow = aout + (size_t)(b * 2048 + qblk * 128 + q) * 1024 + h * 64 + c0;
#pragma unroll
  for (int k = 0; k < 4; ++k)
    *reinterpret_cast<short8*>(orow + k * 8) =
        *reinterpret_cast<const short8*>(&lo[q][c0 + k * 8]);
}

// ---------------- host ----------------
extern "C" void kernel_launch(void* const* d_in, const int* in_sizes, int n_in,
                              void* d_out, int out_size, void* d_ws, size_t ws_size,
                              hipStream_t stream) {
  const float* x  = (const float*)d_in[0];
  const float* wq = (const float*)d_in[1];
  const float* bq = (const float*)d_in[2];
  const float* wk = (const float*)d_in[3];
  const float* bk = (const float*)d_in[4];
  const float* wv = (const float*)d_in[5];
  const float* bv = (const float*)d_in[6];
  const float* wo = (const float*)d_in[7];
  const float* bo = (const float*)d_in[8];
  float* out = (float*)d_out;

  char* ws = (char*)d_ws;
  // [0,8M): xb (GEMM phase) / poA (attn+merge)  [8M,16M): wt  [16M,+12K): bias3
  // [16M+64K,+24M): qkvb (attn) -> aob reuse    [42.01M,+8M): poB   pl @ 50.40M
  unsigned short* xb    = (unsigned short*)(ws);
  _Float16*       poA   = (_Float16*)(ws);
  unsigned short* wt    = (unsigned short*)(ws + 8388608);
  float*          bias3 = (float*)(ws + 16777216);
  unsigned short* qkvb  = (unsigned short*)(ws + 16842752);
  unsigned short* aob   = qkvb;
  _Float16*       poB   = (_Float16*)(ws + 42008576);
  const bool s2 = ws_size >= (size_t)51500000;
  float* pl = (float*)(s2 ? (ws + 50397184) : (ws + 42008576));

  // fused prep: wt transpose (4096 blocks) + x cast (4096) + bias pack (1)
  prep_all_kernel<<<8193, 256, 0, stream>>>(x, wq, wk, wv, wo, bq, bk, bv, xb, wt, bias3);

  // fused QKV projection (Q pre-scaled by 0.125*log2e): [4096][3072] bf16
  gemm_bt_kernel<unsigned short, true><<<768, 256, 0, stream>>>(xb, wt, bias3, qkvb, 3072);

  // attention partials + merge -> aob [4096][1024] bf16
  if (s2) {
    attn_kernel<2><<<1024, 256, 0, stream>>>(qkvb, poA, poB, pl);
    merge_kernel<2><<<512, 256, 0, stream>>>(poA, poB, pl, aob);
  } else {
    attn_kernel<1><<<512, 256, 0, stream>>>(qkvb, poA, poB, pl);
    merge_kernel<1><<<512, 256, 0, stream>>>(poA, poB, pl, aob);
  }

  // output projection -> fp32 d_out [4096][1024]
  gemm_bt_kernel<float, false><<<256, 256, 0, stream>>>(aob, wt + (size_t)3072 * 1024, bo, out, 1024);
}

// Round 13
// 115.984 us; speedup vs baseline: 1.5737x; 1.0774x over previous
//
#include <hip/hip_runtime.h>
#include <stdint.h>
#include <stddef.h>

// MHA: x[2,2048,1024] -> QKV proj (bf16 MFMA) -> flash attn (H=16, Dh=64) -> out proj.
// R13: R12's attn inner loop frozen; the 2-way KV split moves in-block: 512-thr blocks,
//      8 waves (4 per kv-half), per-half private 32KB K/V double-buffers (64KB/block,
//      2 blocks/CU = 16 waves/CU unchanged). Merge done in-LDS at kernel end ->
//      partial buffers + merge kernel + ws guard deleted; aob lives in dead xb region.

typedef __attribute__((ext_vector_type(8))) short short8;
typedef __attribute__((ext_vector_type(4))) float f32x4;
typedef __attribute__((ext_vector_type(16))) float f32x16;
typedef __attribute__((ext_vector_type(4))) unsigned short u16x4;

#define MFMA16(a, b, c) __builtin_amdgcn_mfma_f32_16x16x32_bf16((a), (b), (c), 0, 0, 0)
#define MFMA32(a, b, c) __builtin_amdgcn_mfma_f32_32x32x16_bf16((a), (b), (c), 0, 0, 0)
#define AS1 __attribute__((address_space(1)))
#define AS3 __attribute__((address_space(3)))

__device__ __forceinline__ unsigned short f2bf(float f) {
  union { float f; unsigned u; } v; v.f = f;
  unsigned r = v.u + 0x7fffu + ((v.u >> 16) & 1u);   // RNE
  return (unsigned short)(r >> 16);
}

__device__ __forceinline__ float fexp2(float x) {
#if __has_builtin(__builtin_amdgcn_exp2f)
  return __builtin_amdgcn_exp2f(x);     // raw v_exp_f32
#else
  return __builtin_exp2f(x);
#endif
}

__device__ __forceinline__ unsigned cvt_pk_bf16(float lo, float hi) {
  unsigned r;
  asm("v_cvt_pk_bf16_f32 %0, %1, %2" : "=v"(r) : "v"(lo), "v"(hi));
  return r;
}

__device__ __forceinline__ void pl32_swap(unsigned& a, unsigned& b) {
  asm volatile("v_permlane32_swap_b32 %0, %1" : "+v"(a), "+v"(b));
}

__device__ __forceinline__ short8 mk8(unsigned a, unsigned b, unsigned c, unsigned d) {
  union { unsigned u[4]; short8 s; } v;
  v.u[0] = a; v.u[1] = b; v.u[2] = c; v.u[3] = d;
  return v.s;
}

// ---------------- fused prep: [0,4096) prep_w | [4096,8192) cast_x | 8192 pack_bias ----
__global__ __launch_bounds__(256) void prep_all_kernel(const float* __restrict__ x,
                                                       const float* __restrict__ wq,
                                                       const float* __restrict__ wk,
                                                       const float* __restrict__ wv,
                                                       const float* __restrict__ wo,
                                                       const float* __restrict__ bq,
                                                       const float* __restrict__ bk,
                                                       const float* __restrict__ bv,
                                                       unsigned short* __restrict__ xb,
                                                       unsigned short* __restrict__ wt,
                                                       float* __restrict__ bias3) {
  __shared__ unsigned short t_lds[32][33];
  const int bid = blockIdx.x;
  if (bid < 4096) {
    int wsel = bid >> 10;
    int rem = bid & 1023;
    int kb = (rem >> 5) << 5;
    int nb = (rem & 31) << 5;
    const float* W = (wsel == 0) ? wq : (wsel == 1) ? wk : (wsel == 2) ? wv : wo;
    int t = threadIdx.x;
    int r = t >> 3, c = (t & 7) * 4;
    float4 v = *reinterpret_cast<const float4*>(W + (size_t)(kb + r) * 1024 + nb + c);
    t_lds[r][c + 0] = f2bf(v.x);
    t_lds[r][c + 1] = f2bf(v.y);
    t_lds[r][c + 2] = f2bf(v.z);
    t_lds[r][c + 3] = f2bf(v.w);
    __syncthreads();
    u16x4 o;
    o.x = t_lds[c + 0][r]; o.y = t_lds[c + 1][r];
    o.z = t_lds[c + 2][r]; o.w = t_lds[c + 3][r];
    *reinterpret_cast<u16x4*>(wt + (size_t)(wsel * 1024 + nb + r) * 1024 + kb + c) = o;
  } else if (bid < 8192) {
    int i = ((bid - 4096) * 256 + threadIdx.x) * 4;
    float4 v = *reinterpret_cast<const float4*>(x + i);
    u16x4 o;
    o.x = f2bf(v.x); o.y = f2bf(v.y); o.z = f2bf(v.z); o.w = f2bf(v.w);
    *reinterpret_cast<u16x4*>(xb + i) = o;
  } else {
#pragma unroll
    for (int k = 0; k < 12; ++k) {
      int i = k * 256 + threadIdx.x;
      bias3[i] = (i < 1024) ? bq[i] : (i < 2048) ? bk[i - 1024] : bv[i - 2048];
    }
  }
}

// ---------------- GEMM (R4 config): 2-phase dbuf, single barrier per K-step ----------------
template <typename OutT, bool QS>
__global__ __launch_bounds__(256) void gemm_bt_kernel(const unsigned short* __restrict__ A,
                                                      const unsigned short* __restrict__ Bt,
                                                      const float* __restrict__ bias,
                                                      OutT* __restrict__ C, int N) {
  constexpr int K = 1024;
  __shared__ __align__(16) unsigned short a_lds[2][128 * 32];
  __shared__ __align__(16) unsigned short b_lds[2][128 * 32];
  const int nb = N >> 7;
  const int nwg = nb << 5;
  const int cpx = nwg >> 3;
  const int wg = ((int)blockIdx.x & 7) * cpx + ((int)blockIdx.x >> 3);  // XCD swizzle
  const int bm = wg / nb;
  const int bn = wg % nb;
  const int m0 = bm << 7, n0 = bn << 7;
  const int tid = threadIdx.x;
  const int w = tid >> 6, l = tid & 63;
  const int lr = l & 15, lg = l >> 4;
  const int wm = (w >> 1) << 6, wn = (w & 1) << 6;

  const int q0 = w * 2, q1 = w * 2 + 1;
  const unsigned short* pa0 = A + (size_t)(m0 + q0 * 16 + (l >> 2)) * K + (l & 3) * 8;
  const unsigned short* pa1 = A + (size_t)(m0 + q1 * 16 + (l >> 2)) * K + (l & 3) * 8;
  const unsigned short* pb0 = Bt + (size_t)(n0 + q0 * 16 + (l >> 2)) * K + (l & 3) * 8;
  const unsigned short* pb1 = Bt + (size_t)(n0 + q1 * 16 + (l >> 2)) * K + (l & 3) * 8;

#define GEMM_STAGE(buf, k0)                                                        \
  do {                                                                             \
    __builtin_amdgcn_global_load_lds((const AS1 void*)(pa0 + (k0)),                \
        (AS3 void*)(&a_lds[buf][q0 * 512]), 16, 0, 0);                             \
    __builtin_amdgcn_global_load_lds((const AS1 void*)(pa1 + (k0)),                \
        (AS3 void*)(&a_lds[buf][q1 * 512]), 16, 0, 0);                             \
    __builtin_amdgcn_global_load_lds((const AS1 void*)(pb0 + (k0)),                \
        (AS3 void*)(&b_lds[buf][q0 * 512]), 16, 0, 0);                             \
    __builtin_amdgcn_global_load_lds((const AS1 void*)(pb1 + (k0)),                \
        (AS3 void*)(&b_lds[buf][q1 * 512]), 16, 0, 0);                             \
  } while (0)

  f32x4 acc[4][4] = {};
  GEMM_STAGE(0, 0);
  __syncthreads();

  int cur = 0;
  for (int k0 = 0; k0 < K; k0 += 32) {
    if (k0 + 32 < K) GEMM_STAGE(cur ^ 1, k0 + 32);
    short8 af[4], bfr[4];
#pragma unroll
    for (int i = 0; i < 4; ++i)
      af[i] = *reinterpret_cast<const short8*>(&a_lds[cur][(wm + i * 16 + lr) * 32 + lg * 8]);
#pragma unroll
    for (int i = 0; i < 4; ++i)
      bfr[i] = *reinterpret_cast<const short8*>(&b_lds[cur][(wn + i * 16 + lr) * 32 + lg * 8]);
#pragma unroll
    for (int i = 0; i < 4; ++i)
#pragma unroll
      for (int j = 0; j < 4; ++j)
        acc[i][j] = MFMA16(af[i], bfr[j], acc[i][j]);
    __syncthreads();
    cur ^= 1;
  }
#undef GEMM_STAGE

  const float scale = (QS && n0 < 1024) ? 0.18033688011111f : 1.0f;  // 0.125*log2e
#pragma unroll
  for (int i = 0; i < 4; ++i) {
#pragma unroll
    for (int j = 0; j < 4; ++j) {
#pragma unroll
      for (int r = 0; r < 4; ++r) {
        int m = m0 + wm + i * 16 + lg * 4 + r;
        int n = n0 + wn + j * 16 + lr;
        float val = (acc[i][j][r] + bias[n]) * scale;
        if constexpr (sizeof(OutT) == 2) {
          C[(size_t)m * N + n] = (OutT)f2bf(val);
        } else {
          C[(size_t)m * N + n] = val;
        }
      }
    }
  }
}

// ---------------- flash attention, in-block KV split ----------------
__device__ __forceinline__ void stage_v(char* vw, int pi, int vd0, short8 va, short8 vb) {
  union { short8 s; unsigned u[4]; } ua, ub;
  ua.s = va; ub.s = vb;
#pragma unroll
  for (int jr = 0; jr < 4; ++jr) {
    unsigned w0 = __builtin_amdgcn_perm(ub.u[jr], ua.u[jr], 0x05040100u);  // lo halves
    unsigned w1 = __builtin_amdgcn_perm(ub.u[jr], ua.u[jr], 0x07060302u);  // hi halves
    int d0 = vd0 + 2 * jr, d1 = d0 + 1;
    *reinterpret_cast<unsigned*>(vw + d0 * 128 + ((4 * pi) ^ ((d0 & 7) << 4))) = w0;
    *reinterpret_cast<unsigned*>(vw + d1 * 128 + ((4 * pi) ^ ((d1 & 7) << 4))) = w1;
  }
}

// grid 512 = (b,h)[32] x qblk[16]; 512 threads = 8 waves; waves 0-3 kv-half 0,
// waves 4-7 kv-half 1 (t in [kv*1024, kv*1024+1024), 16 tiles of 64). Per-half private
// 32KB K/V double-buffers. Fixed-base softmax (p=exp2(s), Q pre-scaled into log2
// domain); l via ones-MFMA. Halves merged in-LDS in the epilogue (additive partials).
__global__ __launch_bounds__(512, 4) void attn_kernel(const unsigned short* __restrict__ qkv,
                                                       unsigned short* __restrict__ aout) {
  // layout: half h at h*32768: [K buf0 8K][K buf1 8K][V buf0 8K][V buf1 8K]
  __shared__ __align__(16) char lds[65536];
  const int tid = threadIdx.x;
  const int w = tid >> 6, l = tid & 63;
  const int kv = w >> 2, wsub = w & 3;
  const int lq = l & 31;
  const int hi = l >> 5;
  const int wg = ((int)blockIdx.x & 7) * 64 + ((int)blockIdx.x >> 3);  // XCD swizzle
  const int bh = wg >> 4, qblk = wg & 15;
  const int b = bh >> 4, h = bh & 15;
  const size_t rowbase = (size_t)b * 2048;
  const int q0 = qblk * 128 + wsub * 32;
  const int base = kv << 15;             // per-half LDS region

  // Q fragments (B-operand); Q pre-scaled by 0.125*log2e in GEMM epilogue.
  short8 qf[4];
  {
    const unsigned short* qrow = qkv + (rowbase + q0 + lq) * 3072 + h * 64 + hi * 8;
#pragma unroll
    for (int c = 0; c < 4; ++c)
      qf[c] = *reinterpret_cast<const short8*>(qrow + c * 16);
  }

  // K staging via global_load_lds, pre-swizzled source (R7-verified formula).
  const int colsw = (16 * (l & 7)) ^ ((l >> 3) << 4);
  const char* ksrc = (const char*)(qkv + (rowbase + kv * 1024) * 3072 + 1024 + h * 64) +
                     (size_t)(16 * wsub + (l >> 3)) * 6144 + colsw;
  const int kdst = wsub * 2048;          // wave-uniform byte offset in the 8 KB K plane

  // V staging (reg + perm): half-local lane covers t = {2pi, 2pi+1}, d = vd0..vd0+7.
  const int pi = tid & 31;
  const int vd0 = ((tid >> 5) & 7) * 8;
  const unsigned short* vbase = qkv + (rowbase + kv * 1024) * 3072 + 2048 + h * 64;
  const int swz_lq = (lq & 7) << 4;

  short8 ones;                           // bf16 1.0 x8 (A-operand for l-sum MFMA)
  {
    union { unsigned u[4]; short8 s; } o_;
    o_.u[0] = o_.u[1] = o_.u[2] = o_.u[3] = 0x3F803F80u;
    ones = o_.s;
  }

  f32x16 ot0 = {}, ot1 = {}, lacc = {};

  // prologue: stage tile 0 into buf 0 of own half
  __builtin_amdgcn_global_load_lds((const AS1 void*)ksrc,
                                   (AS3 void*)(lds + base + kdst), 16, 0, 0);
  __builtin_amdgcn_global_load_lds((const AS1 void*)(ksrc + 49152),
                                   (AS3 void*)(lds + base + kdst + 1024), 16, 0, 0);
  ksrc += 393216;
  {
    short8 va = *reinterpret_cast<const short8*>(vbase + (size_t)(2 * pi) * 3072 + vd0);
    short8 vb = *reinterpret_cast<const short8*>(vbase + (size_t)(2 * pi + 1) * 3072 + vd0);
    stage_v(lds + base + 16384, pi, vd0, va, vb);
  }

  int cur = 0;
  for (int t0 = 0; t0 < 1024; t0 += 64) {
    __syncthreads();   // drains K gll + V ds_writes into buf[cur]; prev readers done
    const bool more = (t0 + 64) < 1024;
    short8 vna, vnb;
    if (more) {
      char* kd = lds + base + ((cur ^ 1) << 13) + kdst;
      __builtin_amdgcn_global_load_lds((const AS1 void*)ksrc, (AS3 void*)kd, 16, 0, 0);
      __builtin_amdgcn_global_load_lds((const AS1 void*)(ksrc + 49152),
                                       (AS3 void*)(kd + 1024), 16, 0, 0);
      ksrc += 393216;
      vna = *reinterpret_cast<const short8*>(vbase + (size_t)(t0 + 64 + 2 * pi) * 3072 + vd0);
      vnb = *reinterpret_cast<const short8*>(vbase + (size_t)(t0 + 65 + 2 * pi) * 3072 + vd0);
    }
    const char* kl = lds + base + (cur << 13);
    const char* vl = lds + base + 16384 + (cur << 13);

    // --- QK^T (swapped): lane owns S^T[.][q=lq] ---
    f32x16 s0 = {}, s1 = {};
    __builtin_amdgcn_s_setprio(1);
#pragma unroll
    for (int c = 0; c < 4; ++c) {
      short8 kf0 = *reinterpret_cast<const short8*>(kl + lq * 128 + ((c * 32 + hi * 16) ^ swz_lq));
      short8 kf1 = *reinterpret_cast<const short8*>(kl + (32 + lq) * 128 + ((c * 32 + hi * 16) ^ swz_lq));
      s0 = MFMA32(kf0, qf[c], s0);
      s1 = MFMA32(kf1, qf[c], s1);
    }
    __builtin_amdgcn_s_setprio(0);

    // stage next V into buf^1 (overlaps softmax/PV)
    if (more) stage_v(lds + base + 16384 + ((cur ^ 1) << 13), pi, vd0, vna, vnb);

    // --- fused per-quadrant: exp2 x8 -> pf -> {PV MFMAs, l-MFMA} ---
#pragma unroll
    for (int c = 0; c < 4; ++c) {
      float t0_, t1_, t2_, t3_, t4_, t5_, t6_, t7_;
      if (c < 2) {
        const int o = c * 8;
        t0_ = fexp2(s0[o + 0]); t1_ = fexp2(s0[o + 1]);
        t2_ = fexp2(s0[o + 2]); t3_ = fexp2(s0[o + 3]);
        t4_ = fexp2(s0[o + 4]); t5_ = fexp2(s0[o + 5]);
        t6_ = fexp2(s0[o + 6]); t7_ = fexp2(s0[o + 7]);
      } else {
        const int o = (c - 2) * 8;
        t0_ = fexp2(s1[o + 0]); t1_ = fexp2(s1[o + 1]);
        t2_ = fexp2(s1[o + 2]); t3_ = fexp2(s1[o + 3]);
        t4_ = fexp2(s1[o + 4]); t5_ = fexp2(s1[o + 5]);
        t6_ = fexp2(s1[o + 6]); t7_ = fexp2(s1[o + 7]);
      }
      unsigned a0 = cvt_pk_bf16(t0_, t1_), a1 = cvt_pk_bf16(t4_, t5_);
      unsigned b0 = cvt_pk_bf16(t2_, t3_), b1 = cvt_pk_bf16(t6_, t7_);
      pl32_swap(a0, a1); pl32_swap(b0, b1);
      short8 pfc = mk8(a0, b0, a1, b1);
      short8 vf0 = *reinterpret_cast<const short8*>(vl + lq * 128 + ((c * 32 + hi * 16) ^ swz_lq));
      short8 vf1 = *reinterpret_cast<const short8*>(vl + (32 + lq) * 128 + ((c * 32 + hi * 16) ^ swz_lq));
      __builtin_amdgcn_s_setprio(1);
      ot0 = MFMA32(vf0, pfc, ot0);
      ot1 = MFMA32(vf1, pfc, ot1);
      lacc = MFMA32(ones, pfc, lacc);
      __builtin_amdgcn_s_setprio(0);
    }
    cur ^= 1;
  }

  // ---- in-block merge: half1 -> LDS (f32 O^T + l), half0 adds+normalizes, all store ----
  __syncthreads();                        // all waves done with K/V planes
  float* lbuf = (float*)lds;              // [128 q] l partials from half 1 (dead K buf0)
  if (kv == 1) {
    float* ob = (float*)(lds + 32768 + wsub * 8192);   // own (dead) region: [64 d][32 q]
#pragma unroll
    for (int r = 0; r < 16; ++r) {
      int d = (r & 3) + 8 * (r >> 2) + 4 * hi;
      ob[d * 32 + lq] = ot0[r];
      ob[(32 + d) * 32 + lq] = ot1[r];
    }
    if (hi == 0) lbuf[wsub * 32 + lq] = lacc[0];
  }
  __syncthreads();
  if (kv == 0) {
    const float* ob = (const float*)(lds + 32768 + wsub * 8192);
    const float inv = 1.0f / (lacc[0] + lbuf[wsub * 32 + lq]);
    char* st = lds + 8192;                // [128 q][64 d] bf16 staging (dead half-0 bufs)
    const int qq = wsub * 32 + lq;
    const int swz = (qq & 7) << 4;
#pragma unroll
    for (int r = 0; r < 16; r += 2) {
      int d = (r & 3) + 8 * (r >> 2) + 4 * hi;
      float a0 = (ot0[r] + ob[d * 32 + lq]) * inv;
      float a1 = (ot0[r + 1] + ob[(d + 1) * 32 + lq]) * inv;
      *(unsigned*)(st + qq * 128 + ((2 * d) ^ swz)) = cvt_pk_bf16(a0, a1);
      float b0_ = (ot1[r] + ob[(32 + d) * 32 + lq]) * inv;
      float b1_ = (ot1[r + 1] + ob[(33 + d) * 32 + lq]) * inv;
      *(unsigned*)(st + qq * 128 + ((2 * (32 + d)) ^ swz)) = cvt_pk_bf16(b0_, b1_);
    }
  }
  __syncthreads();
  {
    int row = tid >> 2;                   // 512 threads -> 128 rows x 32 B
    int c2 = (tid & 3) * 2;
    int swzr = (row & 7) << 4;
    const char* src = lds + 8192 + row * 128;
    short8 v0 = *reinterpret_cast<const short8*>(src + ((c2 * 16) ^ swzr));
    short8 v1 = *reinterpret_cast<const short8*>(src + (((c2 + 1) * 16) ^ swzr));
    unsigned short* orow = aout + (rowbase + qblk * 128 + row) * 1024 + h * 64 + c2 * 8;
    *reinterpret_cast<short8*>(orow) = v0;
    *reinterpret_cast<short8*>(orow + 8) = v1;
  }
}

// ---------------- host ----------------
extern "C" void kernel_launch(void* const* d_in, const int* in_sizes, int n_in,
                              void* d_out, int out_size, void* d_ws, size_t ws_size,
                              hipStream_t stream) {
  const float* x  = (const float*)d_in[0];
  const float* wq = (const float*)d_in[1];
  const float* bq = (const float*)d_in[2];
  const float* wk = (const float*)d_in[3];
  const float* bk = (const float*)d_in[4];
  const float* wv = (const float*)d_in[5];
  const float* bv = (const float*)d_in[6];
  const float* wo = (const float*)d_in[7];
  const float* bo = (const float*)d_in[8];
  float* out = (float*)d_out;

  char* ws = (char*)d_ws;
  // [0,8M): xb during GEMM phase; aob (attn output) afterwards (xb dead post-QKV)
  // [8M,16M): wt   [16M,+12K): bias3   [16M+64K, +24M): qkvb
  unsigned short* xb    = (unsigned short*)(ws);
  unsigned short* aob   = (unsigned short*)(ws);
  unsigned short* wt    = (unsigned short*)(ws + 8388608);
  float*          bias3 = (float*)(ws + 16777216);
  unsigned short* qkvb  = (unsigned short*)(ws + 16842752);

  // fused prep: wt transpose (4096 blocks) + x cast (4096) + bias pack (1)
  prep_all_kernel<<<8193, 256, 0, stream>>>(x, wq, wk, wv, wo, bq, bk, bv, xb, wt, bias3);

  // fused QKV projection (Q pre-scaled by 0.125*log2e): [4096][3072] bf16
  gemm_bt_kernel<unsigned short, true><<<768, 256, 0, stream>>>(xb, wt, bias3, qkvb, 3072);

  // attention (in-block kv split + merge) -> aob [4096][1024] bf16
  attn_kernel<<<512, 512, 0, stream>>>(qkvb, aob);

  // output projection -> fp32 d_out [4096][1024]
  gemm_bt_kernel<float, false><<<256, 256, 0, stream>>>(aob, wt + (size_t)3072 * 1024, bo, out, 1024);
}